// Round 3
// baseline (677.559 us; speedup 1.0000x reference)
//
#include <hip/hip_runtime.h>
#include <hip/hip_cooperative_groups.h>

namespace cg = cooperative_groups;

#define NN 65536
#define PP 64
#define HH 64
#define FINN 16
#define NG 1024
#define NBLK 512  // cooperative grid: 2 blocks/CU, 2 graphs/block
#define EPSF 1e-5f
#define C1 0.0625f
#define NREP 32  // stats accumulator replicas (contention spread)

typedef short bf16x8 __attribute__((ext_vector_type(8)));
typedef short s16x4 __attribute__((ext_vector_type(4)));
typedef float f32x4 __attribute__((ext_vector_type(4)));
typedef unsigned short u16;

#define MFMA(a, b, c) __builtin_amdgcn_mfma_f32_16x16x32_bf16(a, b, c, 0, 0, 0)

__device__ __forceinline__ u16 f2bf(float x) {
  union { float f; unsigned u; } v; v.f = x; return (u16)(v.u >> 16);
}
__device__ __forceinline__ float bf2f(u16 h) {
  union { float f; unsigned u; } v; v.u = ((unsigned)h) << 16; return v.f;
}
__device__ __forceinline__ void split2(float x, u16& h, u16& l) {
  h = f2bf(x); l = f2bf(x - bf2f(h));
}
// swizzled index into a 64x64 u16 LDS tile: 16B granules XOR'd by row&7
__device__ __forceinline__ int XIDX(int r, int c) {
  return r * 64 + ((((c >> 3) ^ (r & 7)) << 3) | (c & 7));
}

// Build local adjacency (multiplicity) for this graph into Adj (bf16, swizzled).
__device__ __forceinline__ void build_adj(const int* __restrict__ src, int g,
                                          int r, u16* Adj) {
  bf16x8 z = {0, 0, 0, 0, 0, 0, 0, 0};
#pragma unroll
  for (int q = 0; q < 8; q++) *(bf16x8*)&Adj[r * 64 + q * 8] = z;
  const int4* s4 = (const int4*)(src + (size_t)g * 1024 + (size_t)r * 16);
  int4 a0 = s4[0], a1 = s4[1], a2 = s4[2], a3 = s4[3];
  int b0 = g * 64;
  int ss[16] = {a0.x - b0, a0.y - b0, a0.z - b0, a0.w - b0,
                a1.x - b0, a1.y - b0, a1.z - b0, a1.w - b0,
                a2.x - b0, a2.y - b0, a2.z - b0, a2.w - b0,
                a3.x - b0, a3.y - b0, a3.z - b0, a3.w - b0};
#pragma unroll
  for (int e = 0; e < 16; e++) {
    int idx = XIDX(r, ss[e]);
    Adj[idx] = f2bf(bf2f(Adj[idx]) + 1.0f);
  }
}

// ===========================================================================
// FUSED COOPERATIVE KERNEL
// 512 blocks x 256 threads, 2 blocks/CU co-resident; block b owns graphs
// 2b, 2b+1 for the whole network. Pre-BN activations stay in registers as
// MFMA accumulator fragments (thread: 4 nodes x 4 channels per graph).
// Layer boundaries = grid.sync(). Stats buffer is touched ONLY via
// device-scope atomicAdd (write) and agent-scope atomic loads (read) --
// required for cross-XCD coherence inside a single kernel (L2s not coherent).
// ===========================================================================
struct KP {
  const float* feat; const int* src;
  const u16 *W1h, *W1l, *W2h, *W2l, *W3h, *W3l;
  const u16 *T1h, *T1l, *P1h, *P1l, *T2h, *T2l, *P2h, *P2l;
  const float *c1b, *bn1g, *bn1b;
  const float *e1tb, *e1pb, *bne1g, *bne1b;
  const float *c2b, *bn2g, *bn2b;
  const float *e2tb, *e2pb, *bne2g, *bne2b;
  const float *c3b, *bn3g, *bn3b;
  float* stats;  // 5 x NREP x 128
  float* out;
};

__global__ __launch_bounds__(256, 2) void k_fused(KP p) {
  // 56 KB LDS pool, manually laid out (aliased between cheb and econv):
  //  [0..4095]=NMh [4096..8191]=NMl [8192..12287]=X0h [12288..16383]=X0l
  //  [16384..20479]=X1h [20480..24575]=X1l [24576..28671]=Adj
  //  econv aliases: Tf(float[64*68]) over X0h..X1h, sW(u32[256]) over X1l
  __shared__ __align__(16) u16 SH[28672];
  __shared__ float sstats[128];
  u16* NMh = SH;
  u16* NMl = SH + 4096;
  u16* X0h = SH + 8192;
  u16* X0l = SH + 12288;
  u16* X1h = SH + 16384;
  u16* X1l = SH + 20480;
  u16* Adj = SH + 24576;
  float* Tf = (float*)(SH + 8192);
  unsigned* sW = (unsigned*)(SH + 20480);

  const int t = threadIdx.x;
  const int L = t & 63;
  const int w = __builtin_amdgcn_readfirstlane(t >> 6);
  const int ml = L & 15, kq = L >> 4;
  const int c0 = w * 16 + kq * 4;  // this thread's 4 output channels

  f32x4 ya[4], yb[4];  // pre-BN y frags: [nt] -> node nt*16+ml, chans c0..c0+3
  const int ga = blockIdx.x * 2, gb = ga + 1;

  cg::grid_group grid = cg::this_grid();
  auto gsync = [&]() { __threadfence(); grid.sync(); };

  // Replica-sum this boundary's stats into LDS. Agent-scope atomic loads
  // bypass the (non-coherent) local L2 so post-sync values are seen.
  auto rep_red = [&](const float* sb) {
    if (t < 128) {
      float s = 0.f;
#pragma unroll
      for (int r = 0; r < NREP; r++)
        s += __hip_atomic_load(sb + (size_t)r * 128 + t, __ATOMIC_RELAXED,
                               __HIP_MEMORY_SCOPE_AGENT);
      sstats[t] = s;
    }
  };

  auto stats_acc = [&](f32x4 (&y)[4], int g, float* so) {
    float s1[4] = {0, 0, 0, 0}, s2[4] = {0, 0, 0, 0};
#pragma unroll
    for (int nt = 0; nt < 4; nt++)
#pragma unroll
      for (int i = 0; i < 4; i++) {
        s1[i] += y[nt][i];
        s2[i] += y[nt][i] * y[nt][i];
      }
#pragma unroll
    for (int i = 0; i < 4; i++)
#pragma unroll
      for (int off = 1; off < 16; off <<= 1) {
        s1[i] += __shfl_xor(s1[i], off, 64);
        s2[i] += __shfl_xor(s2[i], off, 64);
      }
    if (ml == 0) {
      float* pr = so + (size_t)(g & (NREP - 1)) * 128 + c0;
#pragma unroll
      for (int i = 0; i < 4; i++) {
        atomicAdd(pr + i, s1[i]);
        atomicAdd(pr + 64 + i, s2[i]);
      }
    }
  };

  // BN+ReLU directly from accumulator frags -> split-bf16 LDS tiles.
  auto bn_frag = [&](f32x4 (&y)[4], const float* gam, const float* bet,
                     u16* CMh, u16* CMl) {
    const float inv = 1.0f / (float)NN;
    float sc[4], sh[4];
#pragma unroll
    for (int i = 0; i < 4; i++) {
      int c = c0 + i;
      float s1 = sstats[c], s2 = sstats[64 + c];
      float mu = s1 * inv;
      float var = fmaf(s2, inv, -mu * mu);
      sc[i] = gam[c] * rsqrtf(var + EPSF);
      sh[i] = fmaf(-mu, sc[i], bet[c]);
    }
#pragma unroll
    for (int nt = 0; nt < 4; nt++) {
      int node = nt * 16 + ml;
      u16 hh[4], ll[4];
      s16x4 vh, vl;
#pragma unroll
      for (int i = 0; i < 4; i++) {
        float h = fmaxf(fmaf(sc[i], y[nt][i], sh[i]), 0.f);
        split2(h, hh[i], ll[i]);
        vh[i] = (short)hh[i]; vl[i] = (short)ll[i];
      }
      *(s16x4*)&NMh[XIDX(node, c0)] = vh;
      *(s16x4*)&NMl[XIDX(node, c0)] = vl;
      if (CMh) {
#pragma unroll
        for (int i = 0; i < 4; i++) {
          CMh[XIDX(c0 + i, node)] = hh[i];
          CMl[XIDX(c0 + i, node)] = ll[i];
        }
      }
    }
  };

  // ---- cheb layer CI=64 (W folded [W0-W2|W1|W2], K=192) ----
  auto cheb64_graph = [&](int g, f32x4 (&y)[4], const u16* wh, const u16* wl,
                          const float* bias, const float* gam,
                          const float* bet, float* so) {
    bn_frag(y, gam, bet, X0h, X0l);
    if (w == 3) build_adj(p.src, g, L, Adj);
    __syncthreads();

    f32x4 acc[4] = {};
    auto yacc = [&](int kbase) {
      const u16* whp = wh + (size_t)(w * 16 + ml) * 192 + kq * 8 + kbase;
      const u16* wlp = wl + (size_t)(w * 16 + ml) * 192 + kq * 8 + kbase;
#pragma unroll
      for (int kt = 0; kt < 2; kt++) {
        bf16x8 ah = *(const bf16x8*)(whp + kt * 32);
        bf16x8 al = *(const bf16x8*)(wlp + kt * 32);
        int kk = kt * 32 + kq * 8;
#pragma unroll
        for (int nt = 0; nt < 4; nt++) {
          bf16x8 bh = *(const bf16x8*)&NMh[XIDX(nt * 16 + ml, kk)];
          bf16x8 bl = *(const bf16x8*)&NMl[XIDX(nt * 16 + ml, kk)];
          acc[nt] = MFMA(ah, bh, acc[nt]);
          acc[nt] = MFMA(al, bh, acc[nt]);
          acc[nt] = MFMA(ah, bl, acc[nt]);
        }
      }
    };
    auto lap = [&](const u16* Bh, const u16* Bl, float scale, u16* oCh,
                   u16* oCl) {
      f32x4 l[4] = {};
#pragma unroll
      for (int kt = 0; kt < 2; kt++) {
        int kk = kt * 32 + kq * 8;
        bf16x8 aa = *(const bf16x8*)&Adj[XIDX(w * 16 + ml, kk)];
#pragma unroll
        for (int nt = 0; nt < 4; nt++) {
          bf16x8 bh = *(const bf16x8*)&Bh[XIDX(nt * 16 + ml, kk)];
          bf16x8 bl = *(const bf16x8*)&Bl[XIDX(nt * 16 + ml, kk)];
          l[nt] = MFMA(aa, bh, l[nt]);
          l[nt] = MFMA(aa, bl, l[nt]);
        }
      }
      int r0 = w * 16 + kq * 4;
#pragma unroll
      for (int nt = 0; nt < 4; nt++) {
        int c = nt * 16 + ml;
        u16 hh[4], ll[4];
#pragma unroll
        for (int i = 0; i < 4; i++) {
          split2(l[nt][i] * scale, hh[i], ll[i]);
          NMh[XIDX(r0 + i, c)] = hh[i];
          NMl[XIDX(r0 + i, c)] = ll[i];
        }
        if (oCh) {
          s16x4 vh, vl;
#pragma unroll
          for (int i = 0; i < 4; i++) {
            vh[i] = (short)hh[i]; vl[i] = (short)ll[i];
          }
          *(s16x4*)&oCh[XIDX(c, r0)] = vh;
          *(s16x4*)&oCl[XIDX(c, r0)] = vl;
        }
      }
    };

    yacc(0);                       // X0 vs W0' = W0 - W2
    __syncthreads();
    lap(X0h, X0l, -C1, X1h, X1l);  // X1 = -C1*Adj*X0
    __syncthreads();
    yacc(64);                      // X1 vs W1
    __syncthreads();
    lap(X1h, X1l, -2.0f * C1, nullptr, nullptr);  // Z2 = -2C1*Adj*X1
    __syncthreads();
    yacc(128);                     // Z2 vs W2
    float4 bb = *(const float4*)(bias + c0);
#pragma unroll
    for (int nt = 0; nt < 4; nt++) {
      y[nt][0] = acc[nt][0] + bb.x;
      y[nt][1] = acc[nt][1] + bb.y;
      y[nt][2] = acc[nt][2] + bb.z;
      y[nt][3] = acc[nt][3] + bb.w;
    }
    stats_acc(y, g, so);
  };

  // ---- econv layer ----
  auto econv_graph = [&](int g, f32x4 (&y)[4], const u16* twh, const u16* twl,
                         const u16* pwh, const u16* pwl, const float* tb,
                         const float* pb, const float* gam, const float* bet,
                         float* so) {
    bn_frag(y, gam, bet, nullptr, nullptr);
    {
      int4 v = ((const int4*)(p.src + (size_t)g * 1024))[t];
      int b0 = g * 64;
      sW[t] = (unsigned)(v.x - b0) | ((unsigned)(v.y - b0) << 8) |
              ((unsigned)(v.z - b0) << 16) | ((unsigned)(v.w - b0) << 24);
    }
    __syncthreads();

    f32x4 tA[4] = {}, pA[4] = {};
    const size_t wrow = (size_t)(w * 16 + ml) * 64 + kq * 8;
#pragma unroll
    for (int kt = 0; kt < 2; kt++) {
      bf16x8 ath = *(const bf16x8*)(twh + wrow + kt * 32);
      bf16x8 atl = *(const bf16x8*)(twl + wrow + kt * 32);
      bf16x8 aph = *(const bf16x8*)(pwh + wrow + kt * 32);
      bf16x8 apl = *(const bf16x8*)(pwl + wrow + kt * 32);
      int kk = kt * 32 + kq * 8;
#pragma unroll
      for (int nt = 0; nt < 4; nt++) {
        bf16x8 bh = *(const bf16x8*)&NMh[XIDX(nt * 16 + ml, kk)];
        bf16x8 bl = *(const bf16x8*)&NMl[XIDX(nt * 16 + ml, kk)];
        tA[nt] = MFMA(ath, bh, tA[nt]);
        tA[nt] = MFMA(atl, bh, tA[nt]);
        tA[nt] = MFMA(ath, bl, tA[nt]);
        pA[nt] = MFMA(aph, bh, pA[nt]);
        pA[nt] = MFMA(apl, bh, pA[nt]);
        pA[nt] = MFMA(aph, bl, pA[nt]);
      }
    }
    // T -> LDS [node][ch] stride 68 (own-wave cols; wave-order write->read ok)
#pragma unroll
    for (int nt = 0; nt < 4; nt++) {
      int n = nt * 16 + ml;
      float4 v;
      v.x = tA[nt][0]; v.y = tA[nt][1]; v.z = tA[nt][2]; v.w = tA[nt][3];
      *(float4*)&Tf[n * 68 + c0] = v;
    }
    float4 tbv = *(const float4*)(tb + c0);
    float4 pbv = *(const float4*)(pb + c0);
#pragma unroll
    for (int nt = 0; nt < 4; nt++) {
      int n = nt * 16 + ml;
      unsigned w0 = sW[n * 4], w1 = sW[n * 4 + 1], w2 = sW[n * 4 + 2],
               w3 = sW[n * 4 + 3];
      float4 mn = {3.4e38f, 3.4e38f, 3.4e38f, 3.4e38f};
#pragma unroll
      for (int e = 0; e < 16; e++) {
        unsigned wd = (e < 4) ? w0 : (e < 8) ? w1 : (e < 12) ? w2 : w3;
        int s = (wd >> ((e & 3) * 8)) & 255;
        float4 tv = *(const float4*)&Tf[s * 68 + c0];
        mn.x = fminf(mn.x, tv.x); mn.y = fminf(mn.y, tv.y);
        mn.z = fminf(mn.z, tv.z); mn.w = fminf(mn.w, tv.w);
      }
      y[nt][0] = tA[nt][0] + pA[nt][0] + tbv.x + pbv.x - mn.x;
      y[nt][1] = tA[nt][1] + pA[nt][1] + tbv.y + pbv.y - mn.y;
      y[nt][2] = tA[nt][2] + pA[nt][2] + tbv.z + pbv.z - mn.z;
      y[nt][3] = tA[nt][3] + pA[nt][3] + tbv.w + pbv.w - mn.w;
    }
    stats_acc(y, g, so);
  };

  // ---- cheb layer 1 (feat input, FIN=16, K padded to 64) ----
  auto cheb1_graph = [&](int g, f32x4 (&y)[4]) {
    {
      int n = t >> 2, cc = (t & 3) * 4;
      float4 v = *(const float4*)(p.feat + (size_t)(g * 64 + n) * 16 + cc);
      u16 hh[4], ll[4];
      split2(v.x, hh[0], ll[0]); split2(v.y, hh[1], ll[1]);
      split2(v.z, hh[2], ll[2]); split2(v.w, hh[3], ll[3]);
      s16x4 vh, vl;
#pragma unroll
      for (int i = 0; i < 4; i++) { vh[i] = (short)hh[i]; vl[i] = (short)ll[i]; }
      *(s16x4*)&NMh[XIDX(n, cc)] = vh;
      *(s16x4*)&NMl[XIDX(n, cc)] = vl;
#pragma unroll
      for (int i = 0; i < 4; i++) {
        X0h[XIDX(cc + i, n)] = hh[i];
        X0l[XIDX(cc + i, n)] = ll[i];
      }
    }
    if (w == 0) {
      bf16x8 z = {0, 0, 0, 0, 0, 0, 0, 0};
      *(bf16x8*)&NMh[XIDX(L, 48)] = z;
      *(bf16x8*)&NMh[XIDX(L, 56)] = z;
    } else if (w == 1) {
      bf16x8 z = {0, 0, 0, 0, 0, 0, 0, 0};
      *(bf16x8*)&NMl[XIDX(L, 48)] = z;
      *(bf16x8*)&NMl[XIDX(L, 56)] = z;
    } else if (w == 3) {
      build_adj(p.src, g, L, Adj);
    }
    __syncthreads();
    {  // lap1: X1 = -C1*Adj*X0 -> NM cols 16..31, CM rows 16..31
      f32x4 l0 = {};
#pragma unroll
      for (int kt = 0; kt < 2; kt++) {
        int kk = kt * 32 + kq * 8;
        bf16x8 aa = *(const bf16x8*)&Adj[XIDX(w * 16 + ml, kk)];
        bf16x8 bh = *(const bf16x8*)&X0h[XIDX(ml, kk)];
        bf16x8 bl = *(const bf16x8*)&X0l[XIDX(ml, kk)];
        l0 = MFMA(aa, bh, l0);
        l0 = MFMA(aa, bl, l0);
      }
      int r0 = w * 16 + kq * 4;
      u16 hh[4], ll[4];
#pragma unroll
      for (int i = 0; i < 4; i++) {
        split2(l0[i] * (-C1), hh[i], ll[i]);
        NMh[XIDX(r0 + i, 16 + ml)] = hh[i];
        NMl[XIDX(r0 + i, 16 + ml)] = ll[i];
      }
      s16x4 vh, vl;
#pragma unroll
      for (int i = 0; i < 4; i++) { vh[i] = (short)hh[i]; vl[i] = (short)ll[i]; }
      *(s16x4*)&X0h[XIDX(16 + ml, r0)] = vh;
      *(s16x4*)&X0l[XIDX(16 + ml, r0)] = vl;
    }
    __syncthreads();
    {  // lap2: Z2 = -2C1*Adj*X1 -> NM cols 32..47
      f32x4 l0 = {};
#pragma unroll
      for (int kt = 0; kt < 2; kt++) {
        int kk = kt * 32 + kq * 8;
        bf16x8 aa = *(const bf16x8*)&Adj[XIDX(w * 16 + ml, kk)];
        bf16x8 bh = *(const bf16x8*)&X0h[XIDX(16 + ml, kk)];
        bf16x8 bl = *(const bf16x8*)&X0l[XIDX(16 + ml, kk)];
        l0 = MFMA(aa, bh, l0);
        l0 = MFMA(aa, bl, l0);
      }
      int r0 = w * 16 + kq * 4;
      u16 hh[4], ll[4];
#pragma unroll
      for (int i = 0; i < 4; i++) {
        split2(l0[i] * (-2.0f * C1), hh[i], ll[i]);
        NMh[XIDX(r0 + i, 32 + ml)] = hh[i];
        NMl[XIDX(r0 + i, 32 + ml)] = ll[i];
      }
    }
    __syncthreads();
    f32x4 acc[4] = {};
    const u16* whp = p.W1h + (size_t)(w * 16 + ml) * 64 + kq * 8;
    const u16* wlp = p.W1l + (size_t)(w * 16 + ml) * 64 + kq * 8;
#pragma unroll
    for (int kt = 0; kt < 2; kt++) {
      bf16x8 ah = *(const bf16x8*)(whp + kt * 32);
      bf16x8 al = *(const bf16x8*)(wlp + kt * 32);
      int kk = kt * 32 + kq * 8;
#pragma unroll
      for (int nt = 0; nt < 4; nt++) {
        bf16x8 bh = *(const bf16x8*)&NMh[XIDX(nt * 16 + ml, kk)];
        bf16x8 bl = *(const bf16x8*)&NMl[XIDX(nt * 16 + ml, kk)];
        acc[nt] = MFMA(ah, bh, acc[nt]);
        acc[nt] = MFMA(al, bh, acc[nt]);
        acc[nt] = MFMA(ah, bl, acc[nt]);
      }
    }
    float4 bb = *(const float4*)(p.c1b + c0);
#pragma unroll
    for (int nt = 0; nt < 4; nt++) {
      y[nt][0] = acc[nt][0] + bb.x;
      y[nt][1] = acc[nt][1] + bb.y;
      y[nt][2] = acc[nt][2] + bb.z;
      y[nt][3] = acc[nt][3] + bb.w;
    }
    stats_acc(y, g, p.stats);
  };

  // ---- final BN+ReLU + mean pool from frags ----
  auto pool_graph = [&](int g, f32x4 (&y)[4], const float* gam,
                        const float* bet) {
    const float inv = 1.0f / (float)NN;
    float sc[4], sh[4];
#pragma unroll
    for (int i = 0; i < 4; i++) {
      int c = c0 + i;
      float s1 = sstats[c], s2 = sstats[64 + c];
      float mu = s1 * inv;
      float var = fmaf(s2, inv, -mu * mu);
      sc[i] = gam[c] * rsqrtf(var + EPSF);
      sh[i] = fmaf(-mu, sc[i], bet[c]);
    }
    float s[4] = {0, 0, 0, 0};
#pragma unroll
    for (int nt = 0; nt < 4; nt++)
#pragma unroll
      for (int i = 0; i < 4; i++)
        s[i] += fmaxf(fmaf(sc[i], y[nt][i], sh[i]), 0.f);
#pragma unroll
    for (int i = 0; i < 4; i++)
#pragma unroll
      for (int off = 1; off < 16; off <<= 1) s[i] += __shfl_xor(s[i], off, 64);
    if (ml == 0) {
      float4 o = make_float4(s[0] * (1.f / 64.f), s[1] * (1.f / 64.f),
                             s[2] * (1.f / 64.f), s[3] * (1.f / 64.f));
      *(float4*)(p.out + (size_t)g * 64 + c0) = o;
    }
  };

  // ======================= network =======================
  // L1: cheb1 (stats boundary 0)
  cheb1_graph(ga, ya);
  __syncthreads();
  cheb1_graph(gb, yb);
  gsync();
  // L2: econv1 (bn1; stats boundary 1)
  rep_red(p.stats + 0);
  __syncthreads();
  econv_graph(ga, ya, p.T1h, p.T1l, p.P1h, p.P1l, p.e1tb, p.e1pb, p.bn1g,
              p.bn1b, p.stats + (size_t)1 * NREP * 128);
  __syncthreads();
  econv_graph(gb, yb, p.T1h, p.T1l, p.P1h, p.P1l, p.e1tb, p.e1pb, p.bn1g,
              p.bn1b, p.stats + (size_t)1 * NREP * 128);
  gsync();
  // L3: cheb2 (bne1; stats boundary 2)
  rep_red(p.stats + (size_t)1 * NREP * 128);
  __syncthreads();
  cheb64_graph(ga, ya, p.W2h, p.W2l, p.c2b, p.bne1g, p.bne1b,
               p.stats + (size_t)2 * NREP * 128);
  __syncthreads();
  cheb64_graph(gb, yb, p.W2h, p.W2l, p.c2b, p.bne1g, p.bne1b,
               p.stats + (size_t)2 * NREP * 128);
  gsync();
  // L4: econv2 (bn2; stats boundary 3)
  rep_red(p.stats + (size_t)2 * NREP * 128);
  __syncthreads();
  econv_graph(ga, ya, p.T2h, p.T2l, p.P2h, p.P2l, p.e2tb, p.e2pb, p.bn2g,
              p.bn2b, p.stats + (size_t)3 * NREP * 128);
  __syncthreads();
  econv_graph(gb, yb, p.T2h, p.T2l, p.P2h, p.P2l, p.e2tb, p.e2pb, p.bn2g,
              p.bn2b, p.stats + (size_t)3 * NREP * 128);
  gsync();
  // L5: cheb3 (bne2; stats boundary 4)
  rep_red(p.stats + (size_t)3 * NREP * 128);
  __syncthreads();
  cheb64_graph(ga, ya, p.W3h, p.W3l, p.c3b, p.bne2g, p.bne2b,
               p.stats + (size_t)4 * NREP * 128);
  __syncthreads();
  cheb64_graph(gb, yb, p.W3h, p.W3l, p.c3b, p.bne2g, p.bne2b,
               p.stats + (size_t)4 * NREP * 128);
  gsync();
  // pool (bn3)
  rep_red(p.stats + (size_t)4 * NREP * 128);
  __syncthreads();
  pool_graph(ga, ya, p.bn3g, p.bn3b);
  pool_graph(gb, yb, p.bn3g, p.bn3b);
}

// ===========================================================================
// FALLBACK PATH (round-2 kernels, used if cooperative launch unavailable)
// ===========================================================================
__device__ __forceinline__ void rep_reduce(const float* __restrict__ stats_in,
                                           int t, float* sstats) {
  if (t < 128) {
    float s = 0.f;
    const float* p = stats_in + t;
#pragma unroll
    for (int r = 0; r < NREP; r++) s += p[r * 128];
    sstats[t] = s;
  }
}

__device__ __forceinline__ void stage_load(const float* __restrict__ y_in,
                                           int g, int t, float4* v) {
  int n = t >> 2, c0 = (t & 3) * 16;
  const float* yr = y_in + ((size_t)(g * 64 + n)) * 64 + c0;
#pragma unroll
  for (int q = 0; q < 4; q++) v[q] = ((const float4*)yr)[q];
}

__device__ __forceinline__ void stage_bn2(
    const float4* v, const float* sstats, const float* __restrict__ gam,
    const float* __restrict__ bet, int t, u16* NMh, u16* NMl, u16* CMh,
    u16* CMl) {
  const float inv = 1.0f / (float)NN;
  int n = t >> 2, c0 = (t & 3) * 16;
  u16 hh[16], ll[16];
#pragma unroll
  for (int q = 0; q < 4; q++) {
#pragma unroll
    for (int k = 0; k < 4; k++) {
      int c = c0 + q * 4 + k;
      float s1 = sstats[c], s2 = sstats[64 + c];
      float mu = s1 * inv;
      float var = fmaf(s2, inv, -mu * mu);
      float sc = gam[c] * rsqrtf(var + EPSF);
      float sh = fmaf(-mu, sc, bet[c]);
      float x = (k == 0) ? v[q].x : (k == 1) ? v[q].y : (k == 2) ? v[q].z
                                                                 : v[q].w;
      float h = fmaxf(fmaf(sc, x, sh), 0.f);
      split2(h, hh[q * 4 + k], ll[q * 4 + k]);
    }
  }
  bf16x8 vh0, vh1, vl0, vl1;
#pragma unroll
  for (int k = 0; k < 8; k++) {
    vh0[k] = (short)hh[k]; vl0[k] = (short)ll[k];
    vh1[k] = (short)hh[8 + k]; vl1[k] = (short)ll[8 + k];
  }
  *(bf16x8*)&NMh[XIDX(n, c0)] = vh0;
  *(bf16x8*)&NMh[XIDX(n, c0 + 8)] = vh1;
  *(bf16x8*)&NMl[XIDX(n, c0)] = vl0;
  *(bf16x8*)&NMl[XIDX(n, c0 + 8)] = vl1;
  if (CMh) {
#pragma unroll
    for (int k = 0; k < 16; k++) {
      CMh[XIDX(c0 + k, n)] = hh[k];
      CMl[XIDX(c0 + k, n)] = ll[k];
    }
  }
}

__device__ __forceinline__ void epilogue(f32x4 a0, f32x4 a1, f32x4 a2, f32x4 a3,
                                         const float* __restrict__ bias, int g,
                                         int w, int ml, int kq,
                                         float* __restrict__ y_out,
                                         float* __restrict__ stats_out) {
  float4 bb = *(const float4*)(bias + w * 16 + kq * 4);
  float s1[4] = {0, 0, 0, 0}, s2[4] = {0, 0, 0, 0};
#pragma unroll
  for (int nt = 0; nt < 4; nt++) {
    f32x4 A = (nt == 0) ? a0 : (nt == 1) ? a1 : (nt == 2) ? a2 : a3;
    float4 yv;
    yv.x = A[0] + bb.x; yv.y = A[1] + bb.y;
    yv.z = A[2] + bb.z; yv.w = A[3] + bb.w;
    int n = nt * 16 + ml;
    *(float4*)(y_out + ((size_t)(g * 64 + n)) * 64 + w * 16 + kq * 4) = yv;
    s1[0] += yv.x; s2[0] += yv.x * yv.x;
    s1[1] += yv.y; s2[1] += yv.y * yv.y;
    s1[2] += yv.z; s2[2] += yv.z * yv.z;
    s1[3] += yv.w; s2[3] += yv.w * yv.w;
  }
#pragma unroll
  for (int i = 0; i < 4; i++) {
#pragma unroll
    for (int off = 1; off < 16; off <<= 1) {
      s1[i] += __shfl_xor(s1[i], off, 64);
      s2[i] += __shfl_xor(s2[i], off, 64);
    }
  }
  if (ml == 0) {
    float* pr = stats_out + (size_t)(g & (NREP - 1)) * 128 + w * 16 + kq * 4;
    atomicAdd(pr + 0, s1[0]);
    atomicAdd(pr + 1, s1[1]);
    atomicAdd(pr + 2, s1[2]);
    atomicAdd(pr + 3, s1[3]);
    atomicAdd(pr + 64, s2[0]);
    atomicAdd(pr + 65, s2[1]);
    atomicAdd(pr + 66, s2[2]);
    atomicAdd(pr + 67, s2[3]);
  }
}

__global__ __launch_bounds__(256, 2) void k_cheb64(
    const float* __restrict__ y_in, const float* __restrict__ stats_in,
    const float* __restrict__ gam, const float* __restrict__ bet,
    const int* __restrict__ src, const u16* __restrict__ wh,
    const u16* __restrict__ wl, const float* __restrict__ bias,
    float* __restrict__ y_out, float* __restrict__ stats_out) {
  __shared__ u16 NMh[4096], NMl[4096], C0h[4096], C0l[4096], C1h[4096],
      C1l[4096], Adj[4096];
  __shared__ float sstats[128];
  const int t = threadIdx.x, g = blockIdx.x;
  const int L = t & 63;
  const int w = __builtin_amdgcn_readfirstlane(t >> 6);
  const int ml = L & 15, kq = L >> 4;

  float4 yv4[4];
  stage_load(y_in, g, t, yv4);
  rep_reduce(stats_in, t, sstats);
  if (w == 3) build_adj(src, g, L, Adj);
  __syncthreads();
  stage_bn2(yv4, sstats, gam, bet, t, NMh, NMl, C0h, C0l);
  __syncthreads();

  f32x4 acc0 = {0, 0, 0, 0}, acc1 = {0, 0, 0, 0}, acc2 = {0, 0, 0, 0},
        acc3 = {0, 0, 0, 0};
  const u16* whp = wh + (size_t)(w * 16 + ml) * 192 + kq * 8;
  const u16* wlp = wl + (size_t)(w * 16 + ml) * 192 + kq * 8;

  auto yacc = [&](int kbase) {
#pragma unroll
    for (int kt = 0; kt < 2; kt++) {
      bf16x8 ah = *(const bf16x8*)(whp + kbase + kt * 32);
      bf16x8 al = *(const bf16x8*)(wlp + kbase + kt * 32);
      int kk = kt * 32 + kq * 8;
#pragma unroll
      for (int nt = 0; nt < 4; nt++) {
        int node = nt * 16 + ml;
        bf16x8 bh = *(const bf16x8*)&NMh[XIDX(node, kk)];
        bf16x8 bl = *(const bf16x8*)&NMl[XIDX(node, kk)];
        f32x4& A = (nt == 0) ? acc0 : (nt == 1) ? acc1 : (nt == 2) ? acc2 : acc3;
        A = MFMA(ah, bh, A);
        A = MFMA(al, bh, A);
        A = MFMA(ah, bl, A);
      }
    }
  };

  auto lap = [&](const u16* Bh, const u16* Bl, float scale, u16* oCh, u16* oCl) {
    f32x4 l0 = {0, 0, 0, 0}, l1 = {0, 0, 0, 0}, l2 = {0, 0, 0, 0},
          l3 = {0, 0, 0, 0};
#pragma unroll
    for (int kt = 0; kt < 2; kt++) {
      int kk = kt * 32 + kq * 8;
      bf16x8 aa = *(const bf16x8*)&Adj[XIDX(w * 16 + ml, kk)];
#pragma unroll
      for (int nt = 0; nt < 4; nt++) {
        bf16x8 bh = *(const bf16x8*)&Bh[XIDX(nt * 16 + ml, kk)];
        bf16x8 bl = *(const bf16x8*)&Bl[XIDX(nt * 16 + ml, kk)];
        f32x4& A = (nt == 0) ? l0 : (nt == 1) ? l1 : (nt == 2) ? l2 : l3;
        A = MFMA(aa, bh, A);
        A = MFMA(aa, bl, A);
      }
    }
    int r0 = w * 16 + kq * 4;
#pragma unroll
    for (int nt = 0; nt < 4; nt++) {
      f32x4 A = (nt == 0) ? l0 : (nt == 1) ? l1 : (nt == 2) ? l2 : l3;
      int c = nt * 16 + ml;
      u16 hh[4], ll[4];
#pragma unroll
      for (int i = 0; i < 4; i++) {
        split2(A[i] * scale, hh[i], ll[i]);
        NMh[XIDX(r0 + i, c)] = hh[i];
        NMl[XIDX(r0 + i, c)] = ll[i];
      }
      if (oCh) {
        s16x4 vh, vl;
#pragma unroll
        for (int i = 0; i < 4; i++) { vh[i] = (short)hh[i]; vl[i] = (short)ll[i]; }
        *(s16x4*)&oCh[XIDX(c, r0)] = vh;
        *(s16x4*)&oCl[XIDX(c, r0)] = vl;
      }
    }
  };

  yacc(0);
  __syncthreads();
  lap(C0h, C0l, -C1, C1h, C1l);
  __syncthreads();
  yacc(64);
  __syncthreads();
  lap(C1h, C1l, -2.0f * C1, nullptr, nullptr);
  __syncthreads();
  yacc(128);
  epilogue(acc0, acc1, acc2, acc3, bias, g, w, ml, kq, y_out, stats_out);
}

__global__ __launch_bounds__(256, 4) void k_econv(
    const float* __restrict__ y_in, const float* __restrict__ stats_in,
    const float* __restrict__ gam, const float* __restrict__ bet,
    const int* __restrict__ src, const u16* __restrict__ twh,
    const u16* __restrict__ twl, const u16* __restrict__ pwh,
    const u16* __restrict__ pwl, const float* __restrict__ tb,
    const float* __restrict__ pb, float* __restrict__ y_out,
    float* __restrict__ stats_out) {
  __shared__ u16 NMh[4096], NMl[4096];
  __shared__ float Tf[64 * 68];
  __shared__ unsigned sW[256];
  __shared__ float sstats[128];
  const int t = threadIdx.x, g = blockIdx.x;
  const int L = t & 63;
  const int w = __builtin_amdgcn_readfirstlane(t >> 6);
  const int ml = L & 15, kq = L >> 4;

  float4 yv4[4];
  stage_load(y_in, g, t, yv4);
  {
    const int4* s4 = (const int4*)(src + (size_t)g * 1024);
    int4 v = s4[t];
    int b0 = g * 64;
    sW[t] = (unsigned)(v.x - b0) | ((unsigned)(v.y - b0) << 8) |
            ((unsigned)(v.z - b0) << 16) | ((unsigned)(v.w - b0) << 24);
  }
  rep_reduce(stats_in, t, sstats);
  __syncthreads();
  stage_bn2(yv4, sstats, gam, bet, t, NMh, NMl, nullptr, nullptr);
  __syncthreads();

  f32x4 t0 = {0,0,0,0}, t1 = {0,0,0,0}, t2 = {0,0,0,0}, t3 = {0,0,0,0};
  f32x4 p0 = {0,0,0,0}, p1 = {0,0,0,0}, p2 = {0,0,0,0}, p3 = {0,0,0,0};
  const size_t wrow = (size_t)(w * 16 + ml) * 64 + kq * 8;
#pragma unroll
  for (int kt = 0; kt < 2; kt++) {
    bf16x8 ath = *(const bf16x8*)(twh + wrow + kt * 32);
    bf16x8 atl = *(const bf16x8*)(twl + wrow + kt * 32);
    bf16x8 aph = *(const bf16x8*)(pwh + wrow + kt * 32);
    bf16x8 apl = *(const bf16x8*)(pwl + wrow + kt * 32);
    int kk = kt * 32 + kq * 8;
#pragma unroll
    for (int nt = 0; nt < 4; nt++) {
      int node = nt * 16 + ml;
      bf16x8 bh = *(const bf16x8*)&NMh[XIDX(node, kk)];
      bf16x8 bl = *(const bf16x8*)&NMl[XIDX(node, kk)];
      f32x4& T = (nt == 0) ? t0 : (nt == 1) ? t1 : (nt == 2) ? t2 : t3;
      f32x4& P = (nt == 0) ? p0 : (nt == 1) ? p1 : (nt == 2) ? p2 : p3;
      T = MFMA(ath, bh, T); T = MFMA(atl, bh, T); T = MFMA(ath, bl, T);
      P = MFMA(aph, bh, P); P = MFMA(apl, bh, P); P = MFMA(aph, bl, P);
    }
  }
#pragma unroll
  for (int nt = 0; nt < 4; nt++) {
    f32x4 T = (nt == 0) ? t0 : (nt == 1) ? t1 : (nt == 2) ? t2 : t3;
    int n = nt * 16 + ml;
    float4 v; v.x = T[0]; v.y = T[1]; v.z = T[2]; v.w = T[3];
    *(float4*)&Tf[n * 68 + w * 16 + kq * 4] = v;
  }
  float4 tbv = *(const float4*)(tb + w * 16 + kq * 4);
  float4 pbv = *(const float4*)(pb + w * 16 + kq * 4);
  float s1[4] = {0, 0, 0, 0}, s2[4] = {0, 0, 0, 0};
#pragma unroll
  for (int nt = 0; nt < 4; nt++) {
    int n = nt * 16 + ml;
    unsigned w0 = sW[n * 4], w1 = sW[n * 4 + 1], w2 = sW[n * 4 + 2],
             w3 = sW[n * 4 + 3];
    float4 mn = {3.4e38f, 3.4e38f, 3.4e38f, 3.4e38f};
#pragma unroll
    for (int e = 0; e < 16; e++) {
      unsigned wd = (e < 4) ? w0 : (e < 8) ? w1 : (e < 12) ? w2 : w3;
      int s = (wd >> ((e & 3) * 8)) & 255;
      float4 tv = *(const float4*)&Tf[s * 68 + w * 16 + kq * 4];
      mn.x = fminf(mn.x, tv.x); mn.y = fminf(mn.y, tv.y);
      mn.z = fminf(mn.z, tv.z); mn.w = fminf(mn.w, tv.w);
    }
    f32x4 T = (nt == 0) ? t0 : (nt == 1) ? t1 : (nt == 2) ? t2 : t3;
    f32x4 P = (nt == 0) ? p0 : (nt == 1) ? p1 : (nt == 2) ? p2 : p3;
    float4 yv;
    yv.x = T[0] + P[0] + tbv.x + pbv.x - mn.x;
    yv.y = T[1] + P[1] + tbv.y + pbv.y - mn.y;
    yv.z = T[2] + P[2] + tbv.z + pbv.z - mn.z;
    yv.w = T[3] + P[3] + tbv.w + pbv.w - mn.w;
    *(float4*)(y_out + ((size_t)(g * 64 + n)) * 64 + w * 16 + kq * 4) = yv;
    s1[0] += yv.x; s2[0] += yv.x * yv.x;
    s1[1] += yv.y; s2[1] += yv.y * yv.y;
    s1[2] += yv.z; s2[2] += yv.z * yv.z;
    s1[3] += yv.w; s2[3] += yv.w * yv.w;
  }
#pragma unroll
  for (int i = 0; i < 4; i++) {
#pragma unroll
    for (int off = 1; off < 16; off <<= 1) {
      s1[i] += __shfl_xor(s1[i], off, 64);
      s2[i] += __shfl_xor(s2[i], off, 64);
    }
  }
  if (ml == 0) {
    float* pr = stats_out + (size_t)(g & (NREP - 1)) * 128 + w * 16 + kq * 4;
    atomicAdd(pr + 0, s1[0]);
    atomicAdd(pr + 1, s1[1]);
    atomicAdd(pr + 2, s1[2]);
    atomicAdd(pr + 3, s1[3]);
    atomicAdd(pr + 64, s2[0]);
    atomicAdd(pr + 65, s2[1]);
    atomicAdd(pr + 66, s2[2]);
    atomicAdd(pr + 67, s2[3]);
  }
}

__global__ __launch_bounds__(256, 3) void k_cheb1(
    const float* __restrict__ feat, const int* __restrict__ src,
    const u16* __restrict__ wh, const u16* __restrict__ wl,
    const float* __restrict__ bias, float* __restrict__ y_out,
    float* __restrict__ stats_out) {
  __shared__ u16 NMh[4096], NMl[4096], Ch[4096], Cl[4096], Adj[4096];
  const int t = threadIdx.x, g = blockIdx.x;
  const int L = t & 63;
  const int w = __builtin_amdgcn_readfirstlane(t >> 6);
  const int ml = L & 15, kq = L >> 4;
  {
    int n = t >> 2, c0 = (t & 3) * 4;
    float4 v = *(const float4*)(feat + (size_t)(g * 64 + n) * 16 + c0);
    u16 hh[4], ll[4];
    split2(v.x, hh[0], ll[0]); split2(v.y, hh[1], ll[1]);
    split2(v.z, hh[2], ll[2]); split2(v.w, hh[3], ll[3]);
    s16x4 vh, vl;
#pragma unroll
    for (int i = 0; i < 4; i++) { vh[i] = (short)hh[i]; vl[i] = (short)ll[i]; }
    *(s16x4*)&NMh[XIDX(n, c0)] = vh;
    *(s16x4*)&NMl[XIDX(n, c0)] = vl;
#pragma unroll
    for (int i = 0; i < 4; i++) {
      Ch[XIDX(c0 + i, n)] = hh[i];
      Cl[XIDX(c0 + i, n)] = ll[i];
    }
  }
  if (w == 0) {
    bf16x8 z = {0, 0, 0, 0, 0, 0, 0, 0};
    *(bf16x8*)&NMh[XIDX(L, 48)] = z;
    *(bf16x8*)&NMh[XIDX(L, 56)] = z;
  } else if (w == 1) {
    bf16x8 z = {0, 0, 0, 0, 0, 0, 0, 0};
    *(bf16x8*)&NMl[XIDX(L, 48)] = z;
    *(bf16x8*)&NMl[XIDX(L, 56)] = z;
  } else if (w == 3) {
    build_adj(src, g, L, Adj);
  }
  __syncthreads();
  {
    f32x4 l0 = {0, 0, 0, 0};
#pragma unroll
    for (int kt = 0; kt < 2; kt++) {
      int kk = kt * 32 + kq * 8;
      bf16x8 aa = *(const bf16x8*)&Adj[XIDX(w * 16 + ml, kk)];
      bf16x8 bh = *(const bf16x8*)&Ch[XIDX(ml, kk)];
      bf16x8 bl = *(const bf16x8*)&Cl[XIDX(ml, kk)];
      l0 = MFMA(aa, bh, l0);
      l0 = MFMA(aa, bl, l0);
    }
    int r0 = w * 16 + kq * 4;
    u16 hh[4], ll[4];
#pragma unroll
    for (int i = 0; i < 4; i++) {
      split2(l0[i] * (-C1), hh[i], ll[i]);
      NMh[XIDX(r0 + i, 16 + ml)] = hh[i];
      NMl[XIDX(r0 + i, 16 + ml)] = ll[i];
    }
    s16x4 vh, vl;
#pragma unroll
    for (int i = 0; i < 4; i++) { vh[i] = (short)hh[i]; vl[i] = (short)ll[i]; }
    *(s16x4*)&Ch[XIDX(16 + ml, r0)] = vh;
    *(s16x4*)&Cl[XIDX(16 + ml, r0)] = vl;
  }
  __syncthreads();
  {
    f32x4 l0 = {0, 0, 0, 0};
#pragma unroll
    for (int kt = 0; kt < 2; kt++) {
      int kk = kt * 32 + kq * 8;
      bf16x8 aa = *(const bf16x8*)&Adj[XIDX(w * 16 + ml, kk)];
      bf16x8 bh = *(const bf16x8*)&Ch[XIDX(16 + ml, kk)];
      bf16x8 bl = *(const bf16x8*)&Cl[XIDX(16 + ml, kk)];
      l0 = MFMA(aa, bh, l0);
      l0 = MFMA(aa, bl, l0);
    }
    int r0 = w * 16 + kq * 4;
    u16 hh[4], ll[4];
#pragma unroll
    for (int i = 0; i < 4; i++) {
      split2(l0[i] * (-2.0f * C1), hh[i], ll[i]);
      NMh[XIDX(r0 + i, 32 + ml)] = hh[i];
      NMl[XIDX(r0 + i, 32 + ml)] = ll[i];
    }
  }
  __syncthreads();
  f32x4 acc0 = {0,0,0,0}, acc1 = {0,0,0,0}, acc2 = {0,0,0,0}, acc3 = {0,0,0,0};
  const u16* whp = wh + (size_t)(w * 16 + ml) * 64 + kq * 8;
  const u16* wlp = wl + (size_t)(w * 16 + ml) * 64 + kq * 8;
#pragma unroll
  for (int kt = 0; kt < 2; kt++) {
    bf16x8 ah = *(const bf16x8*)(whp + kt * 32);
    bf16x8 al = *(const bf16x8*)(wlp + kt * 32);
    int kk = kt * 32 + kq * 8;
#pragma unroll
    for (int nt = 0; nt < 4; nt++) {
      int node = nt * 16 + ml;
      bf16x8 bh = *(const bf16x8*)&NMh[XIDX(node, kk)];
      bf16x8 bl = *(const bf16x8*)&NMl[XIDX(node, kk)];
      f32x4& A = (nt == 0) ? acc0 : (nt == 1) ? acc1 : (nt == 2) ? acc2 : acc3;
      A = MFMA(ah, bh, A);
      A = MFMA(al, bh, A);
      A = MFMA(ah, bl, A);
    }
  }
  epilogue(acc0, acc1, acc2, acc3, bias, g, w, ml, kq, y_out, stats_out);
}

__global__ __launch_bounds__(256, 4) void k_pool(
    const float* __restrict__ y_in, const float* __restrict__ stats_in,
    const float* __restrict__ gam, const float* __restrict__ bet,
    float* __restrict__ out) {
  __shared__ float sstats[128];
  int t = threadIdx.x, g = blockIdx.x;
  int n = t & 63;
  int cog = __builtin_amdgcn_readfirstlane(t >> 6);
  const float inv = 1.0f / (float)NN;
  const float* yr = y_in + ((size_t)(g * 64 + n)) * 64 + cog * 16;
  float4 v[4];
#pragma unroll
  for (int q = 0; q < 4; q++) v[q] = ((const float4*)yr)[q];
  rep_reduce(stats_in, t, sstats);
  __syncthreads();
  float sumv = 0.f;
#pragma unroll
  for (int q = 0; q < 4; q++) {
#pragma unroll
    for (int k = 0; k < 4; k++) {
      int j = q * 4 + k;
      int c = cog * 16 + j;
      float s1 = sstats[c], s2 = sstats[64 + c];
      float mu = s1 * inv;
      float var = fmaf(s2, inv, -mu * mu);
      float sc = gam[c] * rsqrtf(var + EPSF);
      float sh = fmaf(-mu, sc, bet[c]);
      float x = (k == 0) ? v[q].x : (k == 1) ? v[q].y : (k == 2) ? v[q].z
                                                                 : v[q].w;
      float h = fmaxf(fmaf(sc, x, sh), 0.f);
      float s = h;
#pragma unroll
      for (int off = 32; off >= 1; off >>= 1) s += __shfl_xor(s, off, 64);
      sumv = (n == j) ? s : sumv;
    }
  }
  if (n < 16) out[(size_t)g * 64 + cog * 16 + n] = sumv * (1.0f / 64.0f);
}

// ---------------------------------------------------------------------------
// Weight prep: fold recurrence, pad, split to bf16 hi/lo; zero replica stats.
// Runs as its OWN dispatch so the kernel-boundary cache flush publishes
// weights + zeroed stats coherently to all XCDs before k_fused.
// ---------------------------------------------------------------------------
__global__ void k_prep(const float* __restrict__ c1w, const float* __restrict__ c2w,
                       const float* __restrict__ c3w, const float* __restrict__ e1t,
                       const float* __restrict__ e1p, const float* __restrict__ e2t,
                       const float* __restrict__ e2p, u16* __restrict__ W1h,
                       u16* __restrict__ W1l, u16* __restrict__ W2h,
                       u16* __restrict__ W2l, u16* __restrict__ W3h,
                       u16* __restrict__ W3l, u16* __restrict__ T1h,
                       u16* __restrict__ T1l, u16* __restrict__ P1h,
                       u16* __restrict__ P1l, u16* __restrict__ T2h,
                       u16* __restrict__ T2l, u16* __restrict__ P2h,
                       u16* __restrict__ P2l, float* __restrict__ stats) {
  int t0 = blockIdx.x * 256 + threadIdx.x;
  int stride = gridDim.x * 256;
  for (int i = t0; i < 5 * NREP * 128; i += stride) stats[i] = 0.f;
  for (int i = t0; i < 4096; i += stride) {
    int r = i >> 6, c = i & 63;
    float v = 0.f;
    if (c < 16) v = c1w[r * 48 + c] - c1w[r * 48 + 32 + c];
    else if (c < 48) v = c1w[r * 48 + c];
    u16 h, l; split2(v, h, l); W1h[i] = h; W1l[i] = l;
  }
  for (int i = t0; i < 12288; i += stride) {
    int r = i / 192, c = i - r * 192;
    float v = (c < 64) ? c2w[r * 192 + c] - c2w[r * 192 + 128 + c]
                       : c2w[r * 192 + c];
    u16 h, l; split2(v, h, l); W2h[i] = h; W2l[i] = l;
  }
  for (int i = t0; i < 12288; i += stride) {
    int r = i / 192, c = i - r * 192;
    float v = (c < 64) ? c3w[r * 192 + c] - c3w[r * 192 + 128 + c]
                       : c3w[r * 192 + c];
    u16 h, l; split2(v, h, l); W3h[i] = h; W3l[i] = l;
  }
  for (int i = t0; i < 4096; i += stride) {
    u16 h, l;
    split2(e1t[i], h, l); T1h[i] = h; T1l[i] = l;
    split2(e1p[i], h, l); P1h[i] = h; P1l[i] = l;
    split2(e2t[i], h, l); T2h[i] = h; T2l[i] = l;
    split2(e2p[i], h, l); P2h[i] = h; P2l[i] = l;
  }
}

// ---------------------------------------------------------------------------
extern "C" void kernel_launch(void* const* d_in, const int* in_sizes, int n_in,
                              void* d_out, int out_size, void* d_ws,
                              size_t ws_size, hipStream_t stream) {
  const float* feat = (const float*)d_in[0];
  const int* src = (const int*)d_in[1];
  const float* cheb1_w = (const float*)d_in[4];
  const float* cheb1_b = (const float*)d_in[5];
  const float* bn1_g = (const float*)d_in[6];
  const float* bn1_b = (const float*)d_in[7];
  const float* e1_tw = (const float*)d_in[8];
  const float* e1_tb = (const float*)d_in[9];
  const float* e1_pw = (const float*)d_in[10];
  const float* e1_pb = (const float*)d_in[11];
  const float* bne1_g = (const float*)d_in[12];
  const float* bne1_b = (const float*)d_in[13];
  const float* cheb2_w = (const float*)d_in[14];
  const float* cheb2_b = (const float*)d_in[15];
  const float* bn2_g = (const float*)d_in[16];
  const float* bn2_b = (const float*)d_in[17];
  const float* e2_tw = (const float*)d_in[18];
  const float* e2_tb = (const float*)d_in[19];
  const float* e2_pw = (const float*)d_in[20];
  const float* e2_pb = (const float*)d_in[21];
  const float* bne2_g = (const float*)d_in[22];
  const float* bne2_b = (const float*)d_in[23];
  const float* cheb3_w = (const float*)d_in[24];
  const float* cheb3_b = (const float*)d_in[25];
  const float* bn3_g = (const float*)d_in[26];
  const float* bn3_b = (const float*)d_in[27];

  float* bufA = (float*)d_ws;
  float* bufB = bufA + (size_t)NN * HH;
  float* stats = bufB + (size_t)NN * HH;  // 5 x NREP x 128 replica stats
  u16* wq = (u16*)(stats + 5 * NREP * 128);
  u16* W1h = wq;           u16* W1l = W1h + 4096;
  u16* W2h = W1l + 4096;   u16* W2l = W2h + 12288;
  u16* W3h = W2l + 12288;  u16* W3l = W3h + 12288;
  u16* T1h = W3l + 12288;  u16* T1l = T1h + 4096;
  u16* P1h = T1l + 4096;   u16* P1l = P1h + 4096;
  u16* T2h = P1l + 4096;   u16* T2l = T2h + 4096;
  u16* P2h = T2l + 4096;   u16* P2l = P2h + 4096;

  k_prep<<<16, 256, 0, stream>>>(cheb1_w, cheb2_w, cheb3_w, e1_tw, e1_pw,
                                 e2_tw, e2_pw, W1h, W1l, W2h, W2l, W3h, W3l,
                                 T1h, T1l, P1h, P1l, T2h, T2l, P2h, P2l,
                                 stats);

  static int coop = -1;
  if (coop < 0) {
    int v = 0;
    if (hipDeviceGetAttribute(&v, hipDeviceAttributeCooperativeLaunch, 0) !=
        hipSuccess)
      v = 0;
    coop = v;
  }

  bool launched = false;
  if (coop) {
    KP p;
    p.feat = feat; p.src = src;
    p.W1h = W1h; p.W1l = W1l; p.W2h = W2h; p.W2l = W2l; p.W3h = W3h; p.W3l = W3l;
    p.T1h = T1h; p.T1l = T1l; p.P1h = P1h; p.P1l = P1l;
    p.T2h = T2h; p.T2l = T2l; p.P2h = P2h; p.P2l = P2l;
    p.c1b = cheb1_b; p.bn1g = bn1_g; p.bn1b = bn1_b;
    p.e1tb = e1_tb; p.e1pb = e1_pb; p.bne1g = bne1_g; p.bne1b = bne1_b;
    p.c2b = cheb2_b; p.bn2g = bn2_g; p.bn2b = bn2_b;
    p.e2tb = e2_tb; p.e2pb = e2_pb; p.bne2g = bne2_g; p.bne2b = bne2_b;
    p.c3b = cheb3_b; p.bn3g = bn3_g; p.bn3b = bn3_b;
    p.stats = stats; p.out = (float*)d_out;
    void* args[] = {&p};
    hipError_t e = hipLaunchCooperativeKernel(
        reinterpret_cast<void*>(k_fused), dim3(NBLK), dim3(256), args, 0,
        stream);
    launched = (e == hipSuccess);
  }

  if (!launched) {  // fallback: round-2 multi-kernel path
    k_cheb1<<<NG, 256, 0, stream>>>(feat, src, W1h, W1l, cheb1_b, bufA,
                                    stats + 0 * NREP * 128);
    k_econv<<<NG, 256, 0, stream>>>(bufA, stats + 0 * NREP * 128, bn1_g, bn1_b,
                                    src, T1h, T1l, P1h, P1l, e1_tb, e1_pb,
                                    bufB, stats + 1 * NREP * 128);
    k_cheb64<<<NG, 256, 0, stream>>>(bufB, stats + 1 * NREP * 128, bne1_g,
                                     bne1_b, src, W2h, W2l, cheb2_b, bufA,
                                     stats + 2 * NREP * 128);
    k_econv<<<NG, 256, 0, stream>>>(bufA, stats + 2 * NREP * 128, bn2_g, bn2_b,
                                    src, T2h, T2l, P2h, P2l, e2_tb, e2_pb,
                                    bufB, stats + 3 * NREP * 128);
    k_cheb64<<<NG, 256, 0, stream>>>(bufB, stats + 3 * NREP * 128, bne2_g,
                                     bne2_b, src, W3h, W3l, cheb3_b, bufA,
                                     stats + 4 * NREP * 128);
    k_pool<<<NG, 256, 0, stream>>>(bufA, stats + 4 * NREP * 128, bn3_g, bn3_b,
                                   (float*)d_out);
  }
}

// Round 4
// 432.955 us; speedup vs baseline: 1.5650x; 1.5650x over previous
//
#include <hip/hip_runtime.h>

#define NN 65536
#define PP 64
#define HH 64
#define FINN 16
#define NG 1024
#define NBLK 512  // cooperative grid: 2 blocks/CU, 2 graphs/block
#define EPSF 1e-5f
#define C1 0.0625f
#define NREP 32  // stats accumulator replicas (contention spread)

typedef short bf16x8 __attribute__((ext_vector_type(8)));
typedef short s16x4 __attribute__((ext_vector_type(4)));
typedef float f32x4 __attribute__((ext_vector_type(4)));
typedef unsigned short u16;

#define MFMA(a, b, c) __builtin_amdgcn_mfma_f32_16x16x32_bf16(a, b, c, 0, 0, 0)

__device__ __forceinline__ u16 f2bf(float x) {
  union { float f; unsigned u; } v; v.f = x; return (u16)(v.u >> 16);
}
__device__ __forceinline__ float bf2f(u16 h) {
  union { float f; unsigned u; } v; v.u = ((unsigned)h) << 16; return v.f;
}
__device__ __forceinline__ void split2(float x, u16& h, u16& l) {
  h = f2bf(x); l = f2bf(x - bf2f(h));
}
// swizzled index into a 64x64 u16 LDS tile: 16B granules XOR'd by row&7
__device__ __forceinline__ int XIDX(int r, int c) {
  return r * 64 + ((((c >> 3) ^ (r & 7)) << 3) | (c & 7));
}

// Build local adjacency (multiplicity) for this graph into Adj (bf16, swizzled).
__device__ __forceinline__ void build_adj(const int* __restrict__ src, int g,
                                          int r, u16* Adj) {
  bf16x8 z = {0, 0, 0, 0, 0, 0, 0, 0};
#pragma unroll
  for (int q = 0; q < 8; q++) *(bf16x8*)&Adj[r * 64 + q * 8] = z;
  const int4* s4 = (const int4*)(src + (size_t)g * 1024 + (size_t)r * 16);
  int4 a0 = s4[0], a1 = s4[1], a2 = s4[2], a3 = s4[3];
  int b0 = g * 64;
  int ss[16] = {a0.x - b0, a0.y - b0, a0.z - b0, a0.w - b0,
                a1.x - b0, a1.y - b0, a1.z - b0, a1.w - b0,
                a2.x - b0, a2.y - b0, a2.z - b0, a2.w - b0,
                a3.x - b0, a3.y - b0, a3.z - b0, a3.w - b0};
#pragma unroll
  for (int e = 0; e < 16; e++) {
    int idx = XIDX(r, ss[e]);
    Adj[idx] = f2bf(bf2f(Adj[idx]) + 1.0f);
  }
}

// ===========================================================================
// FUSED KERNEL with CUSTOM grid barrier (replaces cg::sync, whose coarse
// s_sleep/fence implementation measured ~78us per sync in round 3).
// 512 blocks x 256 threads, 2 blocks/CU co-resident (cooperative launch
// guarantees residency); block b owns graphs 2b, 2b+1. Pre-BN activations
// stay in registers. Stats: device-scope atomicAdd writes (32 replicas),
// agent-scope atomic loads post-barrier (cross-XCD coherent point = L3).
// Barrier: per-boundary counter; __syncthreads' vmcnt(0) drain publishes the
// block's atomics before arrival; thread 0 fetch_add(ACQ_REL) then spins on
// ACQUIRE loads with s_sleep(1) backoff (read spins don't serialize like RMW).
// ===========================================================================
struct KP {
  const float* feat; const int* src;
  const u16 *W1h, *W1l, *W2h, *W2l, *W3h, *W3l;
  const u16 *T1h, *T1l, *P1h, *P1l, *T2h, *T2l, *P2h, *P2l;
  const float *c1b, *bn1g, *bn1b;
  const float *e1tb, *e1pb, *bne1g, *bne1b;
  const float *c2b, *bn2g, *bn2b;
  const float *e2tb, *e2pb, *bne2g, *bne2b;
  const float *c3b, *bn3g, *bn3b;
  float* stats;   // 5 x NREP x 128
  unsigned* bar;  // 8 barrier counters (zeroed by k_prep each iteration)
  float* out;
};

__global__ __launch_bounds__(256, 2) void k_fused(KP p) {
  // 56 KB LDS pool, manually laid out (aliased between cheb and econv):
  //  [0..4095]=NMh [4096..8191]=NMl [8192..12287]=X0h [12288..16383]=X0l
  //  [16384..20479]=X1h [20480..24575]=X1l [24576..28671]=Adj
  //  econv aliases: Tf(float[64*68]) over X0h..X1h, sW(u32[256]) over X1l
  __shared__ __align__(16) u16 SH[28672];
  __shared__ float sstats[128];
  u16* NMh = SH;
  u16* NMl = SH + 4096;
  u16* X0h = SH + 8192;
  u16* X0l = SH + 12288;
  u16* X1h = SH + 16384;
  u16* X1l = SH + 20480;
  u16* Adj = SH + 24576;
  float* Tf = (float*)(SH + 8192);
  unsigned* sW = (unsigned*)(SH + 20480);

  const int t = threadIdx.x;
  const int L = t & 63;
  const int w = __builtin_amdgcn_readfirstlane(t >> 6);
  const int ml = L & 15, kq = L >> 4;
  const int c0 = w * 16 + kq * 4;  // this thread's 4 output channels

  f32x4 ya[4], yb[4];  // pre-BN y frags: [nt] -> node nt*16+ml, chans c0..c0+3
  const int ga = blockIdx.x * 2, gb = ga + 1;

  // Custom grid barrier on counter i. First __syncthreads drains each wave's
  // vmcnt -> this block's stats atomicAdds are at L3 before we arrive.
  auto gbar = [&](int i) {
    __syncthreads();
    if (t == 0) {
      unsigned* c = p.bar + i;
      __hip_atomic_fetch_add(c, 1u, __ATOMIC_ACQ_REL,
                             __HIP_MEMORY_SCOPE_AGENT);
      while (__hip_atomic_load(c, __ATOMIC_ACQUIRE,
                               __HIP_MEMORY_SCOPE_AGENT) < (unsigned)NBLK)
        __builtin_amdgcn_s_sleep(1);
    }
    __syncthreads();
  };

  // Replica-sum this boundary's stats into LDS. Agent-scope atomic loads
  // bypass the (non-coherent) local L2 so post-barrier values are seen.
  auto rep_red = [&](const float* sb) {
    if (t < 128) {
      float s = 0.f;
#pragma unroll
      for (int r = 0; r < NREP; r++)
        s += __hip_atomic_load(sb + (size_t)r * 128 + t, __ATOMIC_RELAXED,
                               __HIP_MEMORY_SCOPE_AGENT);
      sstats[t] = s;
    }
  };

  auto stats_acc = [&](f32x4 (&y)[4], int g, float* so) {
    float s1[4] = {0, 0, 0, 0}, s2[4] = {0, 0, 0, 0};
#pragma unroll
    for (int nt = 0; nt < 4; nt++)
#pragma unroll
      for (int i = 0; i < 4; i++) {
        s1[i] += y[nt][i];
        s2[i] += y[nt][i] * y[nt][i];
      }
#pragma unroll
    for (int i = 0; i < 4; i++)
#pragma unroll
      for (int off = 1; off < 16; off <<= 1) {
        s1[i] += __shfl_xor(s1[i], off, 64);
        s2[i] += __shfl_xor(s2[i], off, 64);
      }
    if (ml == 0) {
      float* pr = so + (size_t)(g & (NREP - 1)) * 128 + c0;
#pragma unroll
      for (int i = 0; i < 4; i++) {
        atomicAdd(pr + i, s1[i]);
        atomicAdd(pr + 64 + i, s2[i]);
      }
    }
  };

  // BN+ReLU directly from accumulator frags -> split-bf16 LDS tiles.
  auto bn_frag = [&](f32x4 (&y)[4], const float* gam, const float* bet,
                     u16* CMh, u16* CMl) {
    const float inv = 1.0f / (float)NN;
    float sc[4], sh[4];
#pragma unroll
    for (int i = 0; i < 4; i++) {
      int c = c0 + i;
      float s1 = sstats[c], s2 = sstats[64 + c];
      float mu = s1 * inv;
      float var = fmaf(s2, inv, -mu * mu);
      sc[i] = gam[c] * rsqrtf(var + EPSF);
      sh[i] = fmaf(-mu, sc[i], bet[c]);
    }
#pragma unroll
    for (int nt = 0; nt < 4; nt++) {
      int node = nt * 16 + ml;
      u16 hh[4], ll[4];
      s16x4 vh, vl;
#pragma unroll
      for (int i = 0; i < 4; i++) {
        float h = fmaxf(fmaf(sc[i], y[nt][i], sh[i]), 0.f);
        split2(h, hh[i], ll[i]);
        vh[i] = (short)hh[i]; vl[i] = (short)ll[i];
      }
      *(s16x4*)&NMh[XIDX(node, c0)] = vh;
      *(s16x4*)&NMl[XIDX(node, c0)] = vl;
      if (CMh) {
#pragma unroll
        for (int i = 0; i < 4; i++) {
          CMh[XIDX(c0 + i, node)] = hh[i];
          CMl[XIDX(c0 + i, node)] = ll[i];
        }
      }
    }
  };

  // ---- cheb layer CI=64 (W folded [W0-W2|W1|W2], K=192) ----
  auto cheb64_graph = [&](int g, f32x4 (&y)[4], const u16* wh, const u16* wl,
                          const float* bias, const float* gam,
                          const float* bet, float* so) {
    bn_frag(y, gam, bet, X0h, X0l);
    if (w == 3) build_adj(p.src, g, L, Adj);
    __syncthreads();

    f32x4 acc[4] = {};
    auto yacc = [&](int kbase) {
      const u16* whp = wh + (size_t)(w * 16 + ml) * 192 + kq * 8 + kbase;
      const u16* wlp = wl + (size_t)(w * 16 + ml) * 192 + kq * 8 + kbase;
#pragma unroll
      for (int kt = 0; kt < 2; kt++) {
        bf16x8 ah = *(const bf16x8*)(whp + kt * 32);
        bf16x8 al = *(const bf16x8*)(wlp + kt * 32);
        int kk = kt * 32 + kq * 8;
#pragma unroll
        for (int nt = 0; nt < 4; nt++) {
          bf16x8 bh = *(const bf16x8*)&NMh[XIDX(nt * 16 + ml, kk)];
          bf16x8 bl = *(const bf16x8*)&NMl[XIDX(nt * 16 + ml, kk)];
          acc[nt] = MFMA(ah, bh, acc[nt]);
          acc[nt] = MFMA(al, bh, acc[nt]);
          acc[nt] = MFMA(ah, bl, acc[nt]);
        }
      }
    };
    auto lap = [&](const u16* Bh, const u16* Bl, float scale, u16* oCh,
                   u16* oCl) {
      f32x4 l[4] = {};
#pragma unroll
      for (int kt = 0; kt < 2; kt++) {
        int kk = kt * 32 + kq * 8;
        bf16x8 aa = *(const bf16x8*)&Adj[XIDX(w * 16 + ml, kk)];
#pragma unroll
        for (int nt = 0; nt < 4; nt++) {
          bf16x8 bh = *(const bf16x8*)&Bh[XIDX(nt * 16 + ml, kk)];
          bf16x8 bl = *(const bf16x8*)&Bl[XIDX(nt * 16 + ml, kk)];
          l[nt] = MFMA(aa, bh, l[nt]);
          l[nt] = MFMA(aa, bl, l[nt]);
        }
      }
      int r0 = w * 16 + kq * 4;
#pragma unroll
      for (int nt = 0; nt < 4; nt++) {
        int c = nt * 16 + ml;
        u16 hh[4], ll[4];
#pragma unroll
        for (int i = 0; i < 4; i++) {
          split2(l[nt][i] * scale, hh[i], ll[i]);
          NMh[XIDX(r0 + i, c)] = hh[i];
          NMl[XIDX(r0 + i, c)] = ll[i];
        }
        if (oCh) {
          s16x4 vh, vl;
#pragma unroll
          for (int i = 0; i < 4; i++) {
            vh[i] = (short)hh[i]; vl[i] = (short)ll[i];
          }
          *(s16x4*)&oCh[XIDX(c, r0)] = vh;
          *(s16x4*)&oCl[XIDX(c, r0)] = vl;
        }
      }
    };

    yacc(0);                       // X0 vs W0' = W0 - W2
    __syncthreads();
    lap(X0h, X0l, -C1, X1h, X1l);  // X1 = -C1*Adj*X0
    __syncthreads();
    yacc(64);                      // X1 vs W1
    __syncthreads();
    lap(X1h, X1l, -2.0f * C1, nullptr, nullptr);  // Z2 = -2C1*Adj*X1
    __syncthreads();
    yacc(128);                     // Z2 vs W2
    float4 bb = *(const float4*)(bias + c0);
#pragma unroll
    for (int nt = 0; nt < 4; nt++) {
      y[nt][0] = acc[nt][0] + bb.x;
      y[nt][1] = acc[nt][1] + bb.y;
      y[nt][2] = acc[nt][2] + bb.z;
      y[nt][3] = acc[nt][3] + bb.w;
    }
    stats_acc(y, g, so);
  };

  // ---- econv layer ----
  auto econv_graph = [&](int g, f32x4 (&y)[4], const u16* twh, const u16* twl,
                         const u16* pwh, const u16* pwl, const float* tb,
                         const float* pb, const float* gam, const float* bet,
                         float* so) {
    bn_frag(y, gam, bet, nullptr, nullptr);
    {
      int4 v = ((const int4*)(p.src + (size_t)g * 1024))[t];
      int b0 = g * 64;
      sW[t] = (unsigned)(v.x - b0) | ((unsigned)(v.y - b0) << 8) |
              ((unsigned)(v.z - b0) << 16) | ((unsigned)(v.w - b0) << 24);
    }
    __syncthreads();

    f32x4 tA[4] = {}, pA[4] = {};
    const size_t wrow = (size_t)(w * 16 + ml) * 64 + kq * 8;
#pragma unroll
    for (int kt = 0; kt < 2; kt++) {
      bf16x8 ath = *(const bf16x8*)(twh + wrow + kt * 32);
      bf16x8 atl = *(const bf16x8*)(twl + wrow + kt * 32);
      bf16x8 aph = *(const bf16x8*)(pwh + wrow + kt * 32);
      bf16x8 apl = *(const bf16x8*)(pwl + wrow + kt * 32);
      int kk = kt * 32 + kq * 8;
#pragma unroll
      for (int nt = 0; nt < 4; nt++) {
        bf16x8 bh = *(const bf16x8*)&NMh[XIDX(nt * 16 + ml, kk)];
        bf16x8 bl = *(const bf16x8*)&NMl[XIDX(nt * 16 + ml, kk)];
        tA[nt] = MFMA(ath, bh, tA[nt]);
        tA[nt] = MFMA(atl, bh, tA[nt]);
        tA[nt] = MFMA(ath, bl, tA[nt]);
        pA[nt] = MFMA(aph, bh, pA[nt]);
        pA[nt] = MFMA(apl, bh, pA[nt]);
        pA[nt] = MFMA(aph, bl, pA[nt]);
      }
    }
    // T -> LDS [node][ch] stride 68 (own-wave cols; wave-order write->read ok)
#pragma unroll
    for (int nt = 0; nt < 4; nt++) {
      int n = nt * 16 + ml;
      float4 v;
      v.x = tA[nt][0]; v.y = tA[nt][1]; v.z = tA[nt][2]; v.w = tA[nt][3];
      *(float4*)&Tf[n * 68 + c0] = v;
    }
    float4 tbv = *(const float4*)(tb + c0);
    float4 pbv = *(const float4*)(pb + c0);
#pragma unroll
    for (int nt = 0; nt < 4; nt++) {
      int n = nt * 16 + ml;
      unsigned w0 = sW[n * 4], w1 = sW[n * 4 + 1], w2 = sW[n * 4 + 2],
               w3 = sW[n * 4 + 3];
      float4 mn = {3.4e38f, 3.4e38f, 3.4e38f, 3.4e38f};
#pragma unroll
      for (int e = 0; e < 16; e++) {
        unsigned wd = (e < 4) ? w0 : (e < 8) ? w1 : (e < 12) ? w2 : w3;
        int s = (wd >> ((e & 3) * 8)) & 255;
        float4 tv = *(const float4*)&Tf[s * 68 + c0];
        mn.x = fminf(mn.x, tv.x); mn.y = fminf(mn.y, tv.y);
        mn.z = fminf(mn.z, tv.z); mn.w = fminf(mn.w, tv.w);
      }
      y[nt][0] = tA[nt][0] + pA[nt][0] + tbv.x + pbv.x - mn.x;
      y[nt][1] = tA[nt][1] + pA[nt][1] + tbv.y + pbv.y - mn.y;
      y[nt][2] = tA[nt][2] + pA[nt][2] + tbv.z + pbv.z - mn.z;
      y[nt][3] = tA[nt][3] + pA[nt][3] + tbv.w + pbv.w - mn.w;
    }
    stats_acc(y, g, so);
  };

  // ---- cheb layer 1 (feat input, FIN=16, K padded to 64) ----
  auto cheb1_graph = [&](int g, f32x4 (&y)[4]) {
    {
      int n = t >> 2, cc = (t & 3) * 4;
      float4 v = *(const float4*)(p.feat + (size_t)(g * 64 + n) * 16 + cc);
      u16 hh[4], ll[4];
      split2(v.x, hh[0], ll[0]); split2(v.y, hh[1], ll[1]);
      split2(v.z, hh[2], ll[2]); split2(v.w, hh[3], ll[3]);
      s16x4 vh, vl;
#pragma unroll
      for (int i = 0; i < 4; i++) { vh[i] = (short)hh[i]; vl[i] = (short)ll[i]; }
      *(s16x4*)&NMh[XIDX(n, cc)] = vh;
      *(s16x4*)&NMl[XIDX(n, cc)] = vl;
#pragma unroll
      for (int i = 0; i < 4; i++) {
        X0h[XIDX(cc + i, n)] = hh[i];
        X0l[XIDX(cc + i, n)] = ll[i];
      }
    }
    if (w == 0) {
      bf16x8 z = {0, 0, 0, 0, 0, 0, 0, 0};
      *(bf16x8*)&NMh[XIDX(L, 48)] = z;
      *(bf16x8*)&NMh[XIDX(L, 56)] = z;
    } else if (w == 1) {
      bf16x8 z = {0, 0, 0, 0, 0, 0, 0, 0};
      *(bf16x8*)&NMl[XIDX(L, 48)] = z;
      *(bf16x8*)&NMl[XIDX(L, 56)] = z;
    } else if (w == 3) {
      build_adj(p.src, g, L, Adj);
    }
    __syncthreads();
    {  // lap1: X1 = -C1*Adj*X0 -> NM cols 16..31, CM rows 16..31
      f32x4 l0 = {};
#pragma unroll
      for (int kt = 0; kt < 2; kt++) {
        int kk = kt * 32 + kq * 8;
        bf16x8 aa = *(const bf16x8*)&Adj[XIDX(w * 16 + ml, kk)];
        bf16x8 bh = *(const bf16x8*)&X0h[XIDX(ml, kk)];
        bf16x8 bl = *(const bf16x8*)&X0l[XIDX(ml, kk)];
        l0 = MFMA(aa, bh, l0);
        l0 = MFMA(aa, bl, l0);
      }
      int r0 = w * 16 + kq * 4;
      u16 hh[4], ll[4];
#pragma unroll
      for (int i = 0; i < 4; i++) {
        split2(l0[i] * (-C1), hh[i], ll[i]);
        NMh[XIDX(r0 + i, 16 + ml)] = hh[i];
        NMl[XIDX(r0 + i, 16 + ml)] = ll[i];
      }
      s16x4 vh, vl;
#pragma unroll
      for (int i = 0; i < 4; i++) { vh[i] = (short)hh[i]; vl[i] = (short)ll[i]; }
      *(s16x4*)&X0h[XIDX(16 + ml, r0)] = vh;
      *(s16x4*)&X0l[XIDX(16 + ml, r0)] = vl;
    }
    __syncthreads();
    {  // lap2: Z2 = -2C1*Adj*X1 -> NM cols 32..47
      f32x4 l0 = {};
#pragma unroll
      for (int kt = 0; kt < 2; kt++) {
        int kk = kt * 32 + kq * 8;
        bf16x8 aa = *(const bf16x8*)&Adj[XIDX(w * 16 + ml, kk)];
        bf16x8 bh = *(const bf16x8*)&X0h[XIDX(16 + ml, kk)];
        bf16x8 bl = *(const bf16x8*)&X0l[XIDX(16 + ml, kk)];
        l0 = MFMA(aa, bh, l0);
        l0 = MFMA(aa, bl, l0);
      }
      int r0 = w * 16 + kq * 4;
      u16 hh[4], ll[4];
#pragma unroll
      for (int i = 0; i < 4; i++) {
        split2(l0[i] * (-2.0f * C1), hh[i], ll[i]);
        NMh[XIDX(r0 + i, 32 + ml)] = hh[i];
        NMl[XIDX(r0 + i, 32 + ml)] = ll[i];
      }
    }
    __syncthreads();
    f32x4 acc[4] = {};
    const u16* whp = p.W1h + (size_t)(w * 16 + ml) * 64 + kq * 8;
    const u16* wlp = p.W1l + (size_t)(w * 16 + ml) * 64 + kq * 8;
#pragma unroll
    for (int kt = 0; kt < 2; kt++) {
      bf16x8 ah = *(const bf16x8*)(whp + kt * 32);
      bf16x8 al = *(const bf16x8*)(wlp + kt * 32);
      int kk = kt * 32 + kq * 8;
#pragma unroll
      for (int nt = 0; nt < 4; nt++) {
        bf16x8 bh = *(const bf16x8*)&NMh[XIDX(nt * 16 + ml, kk)];
        bf16x8 bl = *(const bf16x8*)&NMl[XIDX(nt * 16 + ml, kk)];
        acc[nt] = MFMA(ah, bh, acc[nt]);
        acc[nt] = MFMA(al, bh, acc[nt]);
        acc[nt] = MFMA(ah, bl, acc[nt]);
      }
    }
    float4 bb = *(const float4*)(p.c1b + c0);
#pragma unroll
    for (int nt = 0; nt < 4; nt++) {
      y[nt][0] = acc[nt][0] + bb.x;
      y[nt][1] = acc[nt][1] + bb.y;
      y[nt][2] = acc[nt][2] + bb.z;
      y[nt][3] = acc[nt][3] + bb.w;
    }
    stats_acc(y, g, p.stats);
  };

  // ---- final BN+ReLU + mean pool from frags ----
  auto pool_graph = [&](int g, f32x4 (&y)[4], const float* gam,
                        const float* bet) {
    const float inv = 1.0f / (float)NN;
    float sc[4], sh[4];
#pragma unroll
    for (int i = 0; i < 4; i++) {
      int c = c0 + i;
      float s1 = sstats[c], s2 = sstats[64 + c];
      float mu = s1 * inv;
      float var = fmaf(s2, inv, -mu * mu);
      sc[i] = gam[c] * rsqrtf(var + EPSF);
      sh[i] = fmaf(-mu, sc[i], bet[c]);
    }
    float s[4] = {0, 0, 0, 0};
#pragma unroll
    for (int nt = 0; nt < 4; nt++)
#pragma unroll
      for (int i = 0; i < 4; i++)
        s[i] += fmaxf(fmaf(sc[i], y[nt][i], sh[i]), 0.f);
#pragma unroll
    for (int i = 0; i < 4; i++)
#pragma unroll
      for (int off = 1; off < 16; off <<= 1) s[i] += __shfl_xor(s[i], off, 64);
    if (ml == 0) {
      float4 o = make_float4(s[0] * (1.f / 64.f), s[1] * (1.f / 64.f),
                             s[2] * (1.f / 64.f), s[3] * (1.f / 64.f));
      *(float4*)(p.out + (size_t)g * 64 + c0) = o;
    }
  };

  // ======================= network =======================
  // L1: cheb1 (stats boundary 0)
  cheb1_graph(ga, ya);
  __syncthreads();
  cheb1_graph(gb, yb);
  gbar(0);
  // L2: econv1 (bn1; stats boundary 1)
  rep_red(p.stats + 0);
  __syncthreads();
  econv_graph(ga, ya, p.T1h, p.T1l, p.P1h, p.P1l, p.e1tb, p.e1pb, p.bn1g,
              p.bn1b, p.stats + (size_t)1 * NREP * 128);
  __syncthreads();
  econv_graph(gb, yb, p.T1h, p.T1l, p.P1h, p.P1l, p.e1tb, p.e1pb, p.bn1g,
              p.bn1b, p.stats + (size_t)1 * NREP * 128);
  gbar(1);
  // L3: cheb2 (bne1; stats boundary 2)
  rep_red(p.stats + (size_t)1 * NREP * 128);
  __syncthreads();
  cheb64_graph(ga, ya, p.W2h, p.W2l, p.c2b, p.bne1g, p.bne1b,
               p.stats + (size_t)2 * NREP * 128);
  __syncthreads();
  cheb64_graph(gb, yb, p.W2h, p.W2l, p.c2b, p.bne1g, p.bne1b,
               p.stats + (size_t)2 * NREP * 128);
  gbar(2);
  // L4: econv2 (bn2; stats boundary 3)
  rep_red(p.stats + (size_t)2 * NREP * 128);
  __syncthreads();
  econv_graph(ga, ya, p.T2h, p.T2l, p.P2h, p.P2l, p.e2tb, p.e2pb, p.bn2g,
              p.bn2b, p.stats + (size_t)3 * NREP * 128);
  __syncthreads();
  econv_graph(gb, yb, p.T2h, p.T2l, p.P2h, p.P2l, p.e2tb, p.e2pb, p.bn2g,
              p.bn2b, p.stats + (size_t)3 * NREP * 128);
  gbar(3);
  // L5: cheb3 (bne2; stats boundary 4)
  rep_red(p.stats + (size_t)3 * NREP * 128);
  __syncthreads();
  cheb64_graph(ga, ya, p.W3h, p.W3l, p.c3b, p.bne2g, p.bne2b,
               p.stats + (size_t)4 * NREP * 128);
  __syncthreads();
  cheb64_graph(gb, yb, p.W3h, p.W3l, p.c3b, p.bne2g, p.bne2b,
               p.stats + (size_t)4 * NREP * 128);
  gbar(4);
  // pool (bn3)
  rep_red(p.stats + (size_t)4 * NREP * 128);
  __syncthreads();
  pool_graph(ga, ya, p.bn3g, p.bn3b);
  pool_graph(gb, yb, p.bn3g, p.bn3b);
}

// ===========================================================================
// FALLBACK PATH (round-2 kernels, used if cooperative launch unavailable)
// ===========================================================================
__device__ __forceinline__ void rep_reduce(const float* __restrict__ stats_in,
                                           int t, float* sstats) {
  if (t < 128) {
    float s = 0.f;
    const float* p = stats_in + t;
#pragma unroll
    for (int r = 0; r < NREP; r++) s += p[r * 128];
    sstats[t] = s;
  }
}

__device__ __forceinline__ void stage_load(const float* __restrict__ y_in,
                                           int g, int t, float4* v) {
  int n = t >> 2, c0 = (t & 3) * 16;
  const float* yr = y_in + ((size_t)(g * 64 + n)) * 64 + c0;
#pragma unroll
  for (int q = 0; q < 4; q++) v[q] = ((const float4*)yr)[q];
}

__device__ __forceinline__ void stage_bn2(
    const float4* v, const float* sstats, const float* __restrict__ gam,
    const float* __restrict__ bet, int t, u16* NMh, u16* NMl, u16* CMh,
    u16* CMl) {
  const float inv = 1.0f / (float)NN;
  int n = t >> 2, c0 = (t & 3) * 16;
  u16 hh[16], ll[16];
#pragma unroll
  for (int q = 0; q < 4; q++) {
#pragma unroll
    for (int k = 0; k < 4; k++) {
      int c = c0 + q * 4 + k;
      float s1 = sstats[c], s2 = sstats[64 + c];
      float mu = s1 * inv;
      float var = fmaf(s2, inv, -mu * mu);
      float sc = gam[c] * rsqrtf(var + EPSF);
      float sh = fmaf(-mu, sc, bet[c]);
      float x = (k == 0) ? v[q].x : (k == 1) ? v[q].y : (k == 2) ? v[q].z
                                                                 : v[q].w;
      float h = fmaxf(fmaf(sc, x, sh), 0.f);
      split2(h, hh[q * 4 + k], ll[q * 4 + k]);
    }
  }
  bf16x8 vh0, vh1, vl0, vl1;
#pragma unroll
  for (int k = 0; k < 8; k++) {
    vh0[k] = (short)hh[k]; vl0[k] = (short)ll[k];
    vh1[k] = (short)hh[8 + k]; vl1[k] = (short)ll[8 + k];
  }
  *(bf16x8*)&NMh[XIDX(n, c0)] = vh0;
  *(bf16x8*)&NMh[XIDX(n, c0 + 8)] = vh1;
  *(bf16x8*)&NMl[XIDX(n, c0)] = vl0;
  *(bf16x8*)&NMl[XIDX(n, c0 + 8)] = vl1;
  if (CMh) {
#pragma unroll
    for (int k = 0; k < 16; k++) {
      CMh[XIDX(c0 + k, n)] = hh[k];
      CMl[XIDX(c0 + k, n)] = ll[k];
    }
  }
}

__device__ __forceinline__ void epilogue(f32x4 a0, f32x4 a1, f32x4 a2, f32x4 a3,
                                         const float* __restrict__ bias, int g,
                                         int w, int ml, int kq,
                                         float* __restrict__ y_out,
                                         float* __restrict__ stats_out) {
  float4 bb = *(const float4*)(bias + w * 16 + kq * 4);
  float s1[4] = {0, 0, 0, 0}, s2[4] = {0, 0, 0, 0};
#pragma unroll
  for (int nt = 0; nt < 4; nt++) {
    f32x4 A = (nt == 0) ? a0 : (nt == 1) ? a1 : (nt == 2) ? a2 : a3;
    float4 yv;
    yv.x = A[0] + bb.x; yv.y = A[1] + bb.y;
    yv.z = A[2] + bb.z; yv.w = A[3] + bb.w;
    int n = nt * 16 + ml;
    *(float4*)(y_out + ((size_t)(g * 64 + n)) * 64 + w * 16 + kq * 4) = yv;
    s1[0] += yv.x; s2[0] += yv.x * yv.x;
    s1[1] += yv.y; s2[1] += yv.y * yv.y;
    s1[2] += yv.z; s2[2] += yv.z * yv.z;
    s1[3] += yv.w; s2[3] += yv.w * yv.w;
  }
#pragma unroll
  for (int i = 0; i < 4; i++) {
#pragma unroll
    for (int off = 1; off < 16; off <<= 1) {
      s1[i] += __shfl_xor(s1[i], off, 64);
      s2[i] += __shfl_xor(s2[i], off, 64);
    }
  }
  if (ml == 0) {
    float* pr = stats_out + (size_t)(g & (NREP - 1)) * 128 + w * 16 + kq * 4;
    atomicAdd(pr + 0, s1[0]);
    atomicAdd(pr + 1, s1[1]);
    atomicAdd(pr + 2, s1[2]);
    atomicAdd(pr + 3, s1[3]);
    atomicAdd(pr + 64, s2[0]);
    atomicAdd(pr + 65, s2[1]);
    atomicAdd(pr + 66, s2[2]);
    atomicAdd(pr + 67, s2[3]);
  }
}

__global__ __launch_bounds__(256, 2) void k_cheb64(
    const float* __restrict__ y_in, const float* __restrict__ stats_in,
    const float* __restrict__ gam, const float* __restrict__ bet,
    const int* __restrict__ src, const u16* __restrict__ wh,
    const u16* __restrict__ wl, const float* __restrict__ bias,
    float* __restrict__ y_out, float* __restrict__ stats_out) {
  __shared__ u16 NMh[4096], NMl[4096], C0h[4096], C0l[4096], C1h[4096],
      C1l[4096], Adj[4096];
  __shared__ float sstats[128];
  const int t = threadIdx.x, g = blockIdx.x;
  const int L = t & 63;
  const int w = __builtin_amdgcn_readfirstlane(t >> 6);
  const int ml = L & 15, kq = L >> 4;

  float4 yv4[4];
  stage_load(y_in, g, t, yv4);
  rep_reduce(stats_in, t, sstats);
  if (w == 3) build_adj(src, g, L, Adj);
  __syncthreads();
  stage_bn2(yv4, sstats, gam, bet, t, NMh, NMl, C0h, C0l);
  __syncthreads();

  f32x4 acc0 = {0, 0, 0, 0}, acc1 = {0, 0, 0, 0}, acc2 = {0, 0, 0, 0},
        acc3 = {0, 0, 0, 0};
  const u16* whp = wh + (size_t)(w * 16 + ml) * 192 + kq * 8;
  const u16* wlp = wl + (size_t)(w * 16 + ml) * 192 + kq * 8;

  auto yacc = [&](int kbase) {
#pragma unroll
    for (int kt = 0; kt < 2; kt++) {
      bf16x8 ah = *(const bf16x8*)(whp + kbase + kt * 32);
      bf16x8 al = *(const bf16x8*)(wlp + kbase + kt * 32);
      int kk = kt * 32 + kq * 8;
#pragma unroll
      for (int nt = 0; nt < 4; nt++) {
        int node = nt * 16 + ml;
        bf16x8 bh = *(const bf16x8*)&NMh[XIDX(node, kk)];
        bf16x8 bl = *(const bf16x8*)&NMl[XIDX(node, kk)];
        f32x4& A = (nt == 0) ? acc0 : (nt == 1) ? acc1 : (nt == 2) ? acc2 : acc3;
        A = MFMA(ah, bh, A);
        A = MFMA(al, bh, A);
        A = MFMA(ah, bl, A);
      }
    }
  };

  auto lap = [&](const u16* Bh, const u16* Bl, float scale, u16* oCh, u16* oCl) {
    f32x4 l0 = {0, 0, 0, 0}, l1 = {0, 0, 0, 0}, l2 = {0, 0, 0, 0},
          l3 = {0, 0, 0, 0};
#pragma unroll
    for (int kt = 0; kt < 2; kt++) {
      int kk = kt * 32 + kq * 8;
      bf16x8 aa = *(const bf16x8*)&Adj[XIDX(w * 16 + ml, kk)];
#pragma unroll
      for (int nt = 0; nt < 4; nt++) {
        bf16x8 bh = *(const bf16x8*)&Bh[XIDX(nt * 16 + ml, kk)];
        bf16x8 bl = *(const bf16x8*)&Bl[XIDX(nt * 16 + ml, kk)];
        f32x4& A = (nt == 0) ? l0 : (nt == 1) ? l1 : (nt == 2) ? l2 : l3;
        A = MFMA(aa, bh, A);
        A = MFMA(aa, bl, A);
      }
    }
    int r0 = w * 16 + kq * 4;
#pragma unroll
    for (int nt = 0; nt < 4; nt++) {
      f32x4 A = (nt == 0) ? l0 : (nt == 1) ? l1 : (nt == 2) ? l2 : l3;
      int c = nt * 16 + ml;
      u16 hh[4], ll[4];
#pragma unroll
      for (int i = 0; i < 4; i++) {
        split2(A[i] * scale, hh[i], ll[i]);
        NMh[XIDX(r0 + i, c)] = hh[i];
        NMl[XIDX(r0 + i, c)] = ll[i];
      }
      if (oCh) {
        s16x4 vh, vl;
#pragma unroll
        for (int i = 0; i < 4; i++) { vh[i] = (short)hh[i]; vl[i] = (short)ll[i]; }
        *(s16x4*)&oCh[XIDX(c, r0)] = vh;
        *(s16x4*)&oCl[XIDX(c, r0)] = vl;
      }
    }
  };

  yacc(0);
  __syncthreads();
  lap(C0h, C0l, -C1, C1h, C1l);
  __syncthreads();
  yacc(64);
  __syncthreads();
  lap(C1h, C1l, -2.0f * C1, nullptr, nullptr);
  __syncthreads();
  yacc(128);
  epilogue(acc0, acc1, acc2, acc3, bias, g, w, ml, kq, y_out, stats_out);
}

__global__ __launch_bounds__(256, 4) void k_econv(
    const float* __restrict__ y_in, const float* __restrict__ stats_in,
    const float* __restrict__ gam, const float* __restrict__ bet,
    const int* __restrict__ src, const u16* __restrict__ twh,
    const u16* __restrict__ twl, const u16* __restrict__ pwh,
    const u16* __restrict__ pwl, const float* __restrict__ tb,
    const float* __restrict__ pb, float* __restrict__ y_out,
    float* __restrict__ stats_out) {
  __shared__ u16 NMh[4096], NMl[4096];
  __shared__ float Tf[64 * 68];
  __shared__ unsigned sW[256];
  __shared__ float sstats[128];
  const int t = threadIdx.x, g = blockIdx.x;
  const int L = t & 63;
  const int w = __builtin_amdgcn_readfirstlane(t >> 6);
  const int ml = L & 15, kq = L >> 4;

  float4 yv4[4];
  stage_load(y_in, g, t, yv4);
  {
    const int4* s4 = (const int4*)(src + (size_t)g * 1024);
    int4 v = s4[t];
    int b0 = g * 64;
    sW[t] = (unsigned)(v.x - b0) | ((unsigned)(v.y - b0) << 8) |
            ((unsigned)(v.z - b0) << 16) | ((unsigned)(v.w - b0) << 24);
  }
  rep_reduce(stats_in, t, sstats);
  __syncthreads();
  stage_bn2(yv4, sstats, gam, bet, t, NMh, NMl, nullptr, nullptr);
  __syncthreads();

  f32x4 t0 = {0,0,0,0}, t1 = {0,0,0,0}, t2 = {0,0,0,0}, t3 = {0,0,0,0};
  f32x4 p0 = {0,0,0,0}, p1 = {0,0,0,0}, p2 = {0,0,0,0}, p3 = {0,0,0,0};
  const size_t wrow = (size_t)(w * 16 + ml) * 64 + kq * 8;
#pragma unroll
  for (int kt = 0; kt < 2; kt++) {
    bf16x8 ath = *(const bf16x8*)(twh + wrow + kt * 32);
    bf16x8 atl = *(const bf16x8*)(twl + wrow + kt * 32);
    bf16x8 aph = *(const bf16x8*)(pwh + wrow + kt * 32);
    bf16x8 apl = *(const bf16x8*)(pwl + wrow + kt * 32);
    int kk = kt * 32 + kq * 8;
#pragma unroll
    for (int nt = 0; nt < 4; nt++) {
      int node = nt * 16 + ml;
      bf16x8 bh = *(const bf16x8*)&NMh[XIDX(node, kk)];
      bf16x8 bl = *(const bf16x8*)&NMl[XIDX(node, kk)];
      f32x4& T = (nt == 0) ? t0 : (nt == 1) ? t1 : (nt == 2) ? t2 : t3;
      f32x4& P = (nt == 0) ? p0 : (nt == 1) ? p1 : (nt == 2) ? p2 : p3;
      T = MFMA(ath, bh, T); T = MFMA(atl, bh, T); T = MFMA(ath, bl, T);
      P = MFMA(aph, bh, P); P = MFMA(apl, bh, P); P = MFMA(aph, bl, P);
    }
  }
#pragma unroll
  for (int nt = 0; nt < 4; nt++) {
    f32x4 T = (nt == 0) ? t0 : (nt == 1) ? t1 : (nt == 2) ? t2 : t3;
    int n = nt * 16 + ml;
    float4 v; v.x = T[0]; v.y = T[1]; v.z = T[2]; v.w = T[3];
    *(float4*)&Tf[n * 68 + w * 16 + kq * 4] = v;
  }
  float4 tbv = *(const float4*)(tb + w * 16 + kq * 4);
  float4 pbv = *(const float4*)(pb + w * 16 + kq * 4);
  float s1[4] = {0, 0, 0, 0}, s2[4] = {0, 0, 0, 0};
#pragma unroll
  for (int nt = 0; nt < 4; nt++) {
    int n = nt * 16 + ml;
    unsigned w0 = sW[n * 4], w1 = sW[n * 4 + 1], w2 = sW[n * 4 + 2],
             w3 = sW[n * 4 + 3];
    float4 mn = {3.4e38f, 3.4e38f, 3.4e38f, 3.4e38f};
#pragma unroll
    for (int e = 0; e < 16; e++) {
      unsigned wd = (e < 4) ? w0 : (e < 8) ? w1 : (e < 12) ? w2 : w3;
      int s = (wd >> ((e & 3) * 8)) & 255;
      float4 tv = *(const float4*)&Tf[s * 68 + w * 16 + kq * 4];
      mn.x = fminf(mn.x, tv.x); mn.y = fminf(mn.y, tv.y);
      mn.z = fminf(mn.z, tv.z); mn.w = fminf(mn.w, tv.w);
    }
    f32x4 T = (nt == 0) ? t0 : (nt == 1) ? t1 : (nt == 2) ? t2 : t3;
    f32x4 P = (nt == 0) ? p0 : (nt == 1) ? p1 : (nt == 2) ? p2 : p3;
    float4 yv;
    yv.x = T[0] + P[0] + tbv.x + pbv.x - mn.x;
    yv.y = T[1] + P[1] + tbv.y + pbv.y - mn.y;
    yv.z = T[2] + P[2] + tbv.z + pbv.z - mn.z;
    yv.w = T[3] + P[3] + tbv.w + pbv.w - mn.w;
    *(float4*)(y_out + ((size_t)(g * 64 + n)) * 64 + w * 16 + kq * 4) = yv;
    s1[0] += yv.x; s2[0] += yv.x * yv.x;
    s1[1] += yv.y; s2[1] += yv.y * yv.y;
    s1[2] += yv.z; s2[2] += yv.z * yv.z;
    s1[3] += yv.w; s2[3] += yv.w * yv.w;
  }
#pragma unroll
  for (int i = 0; i < 4; i++) {
#pragma unroll
    for (int off = 1; off < 16; off <<= 1) {
      s1[i] += __shfl_xor(s1[i], off, 64);
      s2[i] += __shfl_xor(s2[i], off, 64);
    }
  }
  if (ml == 0) {
    float* pr = stats_out + (size_t)(g & (NREP - 1)) * 128 + w * 16 + kq * 4;
    atomicAdd(pr + 0, s1[0]);
    atomicAdd(pr + 1, s1[1]);
    atomicAdd(pr + 2, s1[2]);
    atomicAdd(pr + 3, s1[3]);
    atomicAdd(pr + 64, s2[0]);
    atomicAdd(pr + 65, s2[1]);
    atomicAdd(pr + 66, s2[2]);
    atomicAdd(pr + 67, s2[3]);
  }
}

__global__ __launch_bounds__(256, 3) void k_cheb1(
    const float* __restrict__ feat, const int* __restrict__ src,
    const u16* __restrict__ wh, const u16* __restrict__ wl,
    const float* __restrict__ bias, float* __restrict__ y_out,
    float* __restrict__ stats_out) {
  __shared__ u16 NMh[4096], NMl[4096], Ch[4096], Cl[4096], Adj[4096];
  const int t = threadIdx.x, g = blockIdx.x;
  const int L = t & 63;
  const int w = __builtin_amdgcn_readfirstlane(t >> 6);
  const int ml = L & 15, kq = L >> 4;
  {
    int n = t >> 2, c0 = (t & 3) * 4;
    float4 v = *(const float4*)(feat + (size_t)(g * 64 + n) * 16 + c0);
    u16 hh[4], ll[4];
    split2(v.x, hh[0], ll[0]); split2(v.y, hh[1], ll[1]);
    split2(v.z, hh[2], ll[2]); split2(v.w, hh[3], ll[3]);
    s16x4 vh, vl;
#pragma unroll
    for (int i = 0; i < 4; i++) { vh[i] = (short)hh[i]; vl[i] = (short)ll[i]; }
    *(s16x4*)&NMh[XIDX(n, c0)] = vh;
    *(s16x4*)&NMl[XIDX(n, c0)] = vl;
#pragma unroll
    for (int i = 0; i < 4; i++) {
      Ch[XIDX(c0 + i, n)] = hh[i];
      Cl[XIDX(c0 + i, n)] = ll[i];
    }
  }
  if (w == 0) {
    bf16x8 z = {0, 0, 0, 0, 0, 0, 0, 0};
    *(bf16x8*)&NMh[XIDX(L, 48)] = z;
    *(bf16x8*)&NMh[XIDX(L, 56)] = z;
  } else if (w == 1) {
    bf16x8 z = {0, 0, 0, 0, 0, 0, 0, 0};
    *(bf16x8*)&NMl[XIDX(L, 48)] = z;
    *(bf16x8*)&NMl[XIDX(L, 56)] = z;
  } else if (w == 3) {
    build_adj(src, g, L, Adj);
  }
  __syncthreads();
  {
    f32x4 l0 = {0, 0, 0, 0};
#pragma unroll
    for (int kt = 0; kt < 2; kt++) {
      int kk = kt * 32 + kq * 8;
      bf16x8 aa = *(const bf16x8*)&Adj[XIDX(w * 16 + ml, kk)];
      bf16x8 bh = *(const bf16x8*)&Ch[XIDX(ml, kk)];
      bf16x8 bl = *(const bf16x8*)&Cl[XIDX(ml, kk)];
      l0 = MFMA(aa, bh, l0);
      l0 = MFMA(aa, bl, l0);
    }
    int r0 = w * 16 + kq * 4;
    u16 hh[4], ll[4];
#pragma unroll
    for (int i = 0; i < 4; i++) {
      split2(l0[i] * (-C1), hh[i], ll[i]);
      NMh[XIDX(r0 + i, 16 + ml)] = hh[i];
      NMl[XIDX(r0 + i, 16 + ml)] = ll[i];
    }
    s16x4 vh, vl;
#pragma unroll
    for (int i = 0; i < 4; i++) { vh[i] = (short)hh[i]; vl[i] = (short)ll[i]; }
    *(s16x4*)&Ch[XIDX(16 + ml, r0)] = vh;
    *(s16x4*)&Cl[XIDX(16 + ml, r0)] = vl;
  }
  __syncthreads();
  {
    f32x4 l0 = {0, 0, 0, 0};
#pragma unroll
    for (int kt = 0; kt < 2; kt++) {
      int kk = kt * 32 + kq * 8;
      bf16x8 aa = *(const bf16x8*)&Adj[XIDX(w * 16 + ml, kk)];
      bf16x8 bh = *(const bf16x8*)&Ch[XIDX(16 + ml, kk)];
      bf16x8 bl = *(const bf16x8*)&Cl[XIDX(16 + ml, kk)];
      l0 = MFMA(aa, bh, l0);
      l0 = MFMA(aa, bl, l0);
    }
    int r0 = w * 16 + kq * 4;
    u16 hh[4], ll[4];
#pragma unroll
    for (int i = 0; i < 4; i++) {
      split2(l0[i] * (-2.0f * C1), hh[i], ll[i]);
      NMh[XIDX(r0 + i, 32 + ml)] = hh[i];
      NMl[XIDX(r0 + i, 32 + ml)] = ll[i];
    }
  }
  __syncthreads();
  f32x4 acc0 = {0,0,0,0}, acc1 = {0,0,0,0}, acc2 = {0,0,0,0}, acc3 = {0,0,0,0};
  const u16* whp = wh + (size_t)(w * 16 + ml) * 64 + kq * 8;
  const u16* wlp = wl + (size_t)(w * 16 + ml) * 64 + kq * 8;
#pragma unroll
  for (int kt = 0; kt < 2; kt++) {
    bf16x8 ah = *(const bf16x8*)(whp + kt * 32);
    bf16x8 al = *(const bf16x8*)(wlp + kt * 32);
    int kk = kt * 32 + kq * 8;
#pragma unroll
    for (int nt = 0; nt < 4; nt++) {
      int node = nt * 16 + ml;
      bf16x8 bh = *(const bf16x8*)&NMh[XIDX(node, kk)];
      bf16x8 bl = *(const bf16x8*)&NMl[XIDX(node, kk)];
      f32x4& A = (nt == 0) ? acc0 : (nt == 1) ? acc1 : (nt == 2) ? acc2 : acc3;
      A = MFMA(ah, bh, A);
      A = MFMA(al, bh, A);
      A = MFMA(ah, bl, A);
    }
  }
  epilogue(acc0, acc1, acc2, acc3, bias, g, w, ml, kq, y_out, stats_out);
}

__global__ __launch_bounds__(256, 4) void k_pool(
    const float* __restrict__ y_in, const float* __restrict__ stats_in,
    const float* __restrict__ gam, const float* __restrict__ bet,
    float* __restrict__ out) {
  __shared__ float sstats[128];
  int t = threadIdx.x, g = blockIdx.x;
  int n = t & 63;
  int cog = __builtin_amdgcn_readfirstlane(t >> 6);
  const float inv = 1.0f / (float)NN;
  const float* yr = y_in + ((size_t)(g * 64 + n)) * 64 + cog * 16;
  float4 v[4];
#pragma unroll
  for (int q = 0; q < 4; q++) v[q] = ((const float4*)yr)[q];
  rep_reduce(stats_in, t, sstats);
  __syncthreads();
  float sumv = 0.f;
#pragma unroll
  for (int q = 0; q < 4; q++) {
#pragma unroll
    for (int k = 0; k < 4; k++) {
      int j = q * 4 + k;
      int c = cog * 16 + j;
      float s1 = sstats[c], s2 = sstats[64 + c];
      float mu = s1 * inv;
      float var = fmaf(s2, inv, -mu * mu);
      float sc = gam[c] * rsqrtf(var + EPSF);
      float sh = fmaf(-mu, sc, bet[c]);
      float x = (k == 0) ? v[q].x : (k == 1) ? v[q].y : (k == 2) ? v[q].z
                                                                 : v[q].w;
      float h = fmaxf(fmaf(sc, x, sh), 0.f);
      float s = h;
#pragma unroll
      for (int off = 32; off >= 1; off >>= 1) s += __shfl_xor(s, off, 64);
      sumv = (n == j) ? s : sumv;
    }
  }
  if (n < 16) out[(size_t)g * 64 + cog * 16 + n] = sumv * (1.0f / 64.0f);
}

// ---------------------------------------------------------------------------
// Weight prep: fold recurrence, pad, split to bf16 hi/lo; zero replica stats
// and the 8 grid-barrier counters. Runs as its OWN dispatch so the
// kernel-boundary flush publishes everything coherently before k_fused.
// ---------------------------------------------------------------------------
__global__ void k_prep(const float* __restrict__ c1w, const float* __restrict__ c2w,
                       const float* __restrict__ c3w, const float* __restrict__ e1t,
                       const float* __restrict__ e1p, const float* __restrict__ e2t,
                       const float* __restrict__ e2p, u16* __restrict__ W1h,
                       u16* __restrict__ W1l, u16* __restrict__ W2h,
                       u16* __restrict__ W2l, u16* __restrict__ W3h,
                       u16* __restrict__ W3l, u16* __restrict__ T1h,
                       u16* __restrict__ T1l, u16* __restrict__ P1h,
                       u16* __restrict__ P1l, u16* __restrict__ T2h,
                       u16* __restrict__ T2l, u16* __restrict__ P2h,
                       u16* __restrict__ P2l, float* __restrict__ stats,
                       unsigned* __restrict__ bar) {
  int t0 = blockIdx.x * 256 + threadIdx.x;
  int stride = gridDim.x * 256;
  for (int i = t0; i < 5 * NREP * 128; i += stride) stats[i] = 0.f;
  if (t0 < 8) bar[t0] = 0u;
  for (int i = t0; i < 4096; i += stride) {
    int r = i >> 6, c = i & 63;
    float v = 0.f;
    if (c < 16) v = c1w[r * 48 + c] - c1w[r * 48 + 32 + c];
    else if (c < 48) v = c1w[r * 48 + c];
    u16 h, l; split2(v, h, l); W1h[i] = h; W1l[i] = l;
  }
  for (int i = t0; i < 12288; i += stride) {
    int r = i / 192, c = i - r * 192;
    float v = (c < 64) ? c2w[r * 192 + c] - c2w[r * 192 + 128 + c]
                       : c2w[r * 192 + c];
    u16 h, l; split2(v, h, l); W2h[i] = h; W2l[i] = l;
  }
  for (int i = t0; i < 12288; i += stride) {
    int r = i / 192, c = i - r * 192;
    float v = (c < 64) ? c3w[r * 192 + c] - c3w[r * 192 + 128 + c]
                       : c3w[r * 192 + c];
    u16 h, l; split2(v, h, l); W3h[i] = h; W3l[i] = l;
  }
  for (int i = t0; i < 4096; i += stride) {
    u16 h, l;
    split2(e1t[i], h, l); T1h[i] = h; T1l[i] = l;
    split2(e1p[i], h, l); P1h[i] = h; P1l[i] = l;
    split2(e2t[i], h, l); T2h[i] = h; T2l[i] = l;
    split2(e2p[i], h, l); P2h[i] = h; P2l[i] = l;
  }
}

// ---------------------------------------------------------------------------
extern "C" void kernel_launch(void* const* d_in, const int* in_sizes, int n_in,
                              void* d_out, int out_size, void* d_ws,
                              size_t ws_size, hipStream_t stream) {
  const float* feat = (const float*)d_in[0];
  const int* src = (const int*)d_in[1];
  const float* cheb1_w = (const float*)d_in[4];
  const float* cheb1_b = (const float*)d_in[5];
  const float* bn1_g = (const float*)d_in[6];
  const float* bn1_b = (const float*)d_in[7];
  const float* e1_tw = (const float*)d_in[8];
  const float* e1_tb = (const float*)d_in[9];
  const float* e1_pw = (const float*)d_in[10];
  const float* e1_pb = (const float*)d_in[11];
  const float* bne1_g = (const float*)d_in[12];
  const float* bne1_b = (const float*)d_in[13];
  const float* cheb2_w = (const float*)d_in[14];
  const float* cheb2_b = (const float*)d_in[15];
  const float* bn2_g = (const float*)d_in[16];
  const float* bn2_b = (const float*)d_in[17];
  const float* e2_tw = (const float*)d_in[18];
  const float* e2_tb = (const float*)d_in[19];
  const float* e2_pw = (const float*)d_in[20];
  const float* e2_pb = (const float*)d_in[21];
  const float* bne2_g = (const float*)d_in[22];
  const float* bne2_b = (const float*)d_in[23];
  const float* cheb3_w = (const float*)d_in[24];
  const float* cheb3_b = (const float*)d_in[25];
  const float* bn3_g = (const float*)d_in[26];
  const float* bn3_b = (const float*)d_in[27];

  float* bufA = (float*)d_ws;
  float* bufB = bufA + (size_t)NN * HH;
  float* stats = bufB + (size_t)NN * HH;  // 5 x NREP x 128 replica stats
  unsigned* bar = (unsigned*)(stats + 5 * NREP * 128);  // 8 barrier counters
  u16* wq = (u16*)(bar + 8);
  u16* W1h = wq;           u16* W1l = W1h + 4096;
  u16* W2h = W1l + 4096;   u16* W2l = W2h + 12288;
  u16* W3h = W2l + 12288;  u16* W3l = W3h + 12288;
  u16* T1h = W3l + 12288;  u16* T1l = T1h + 4096;
  u16* P1h = T1l + 4096;   u16* P1l = P1h + 4096;
  u16* T2h = P1l + 4096;   u16* T2l = T2h + 4096;
  u16* P2h = T2l + 4096;   u16* P2l = P2h + 4096;

  k_prep<<<16, 256, 0, stream>>>(cheb1_w, cheb2_w, cheb3_w, e1_tw, e1_pw,
                                 e2_tw, e2_pw, W1h, W1l, W2h, W2l, W3h, W3l,
                                 T1h, T1l, P1h, P1l, T2h, T2l, P2h, P2l,
                                 stats, bar);

  static int coop = -1;
  if (coop < 0) {
    int v = 0;
    if (hipDeviceGetAttribute(&v, hipDeviceAttributeCooperativeLaunch, 0) !=
        hipSuccess)
      v = 0;
    coop = v;
  }

  bool launched = false;
  if (coop) {
    KP p;
    p.feat = feat; p.src = src;
    p.W1h = W1h; p.W1l = W1l; p.W2h = W2h; p.W2l = W2l; p.W3h = W3h; p.W3l = W3l;
    p.T1h = T1h; p.T1l = T1l; p.P1h = P1h; p.P1l = P1l;
    p.T2h = T2h; p.T2l = T2l; p.P2h = P2h; p.P2l = P2l;
    p.c1b = cheb1_b; p.bn1g = bn1_g; p.bn1b = bn1_b;
    p.e1tb = e1_tb; p.e1pb = e1_pb; p.bne1g = bne1_g; p.bne1b = bne1_b;
    p.c2b = cheb2_b; p.bn2g = bn2_g; p.bn2b = bn2_b;
    p.e2tb = e2_tb; p.e2pb = e2_pb; p.bne2g = bne2_g; p.bne2b = bne2_b;
    p.c3b = cheb3_b; p.bn3g = bn3_g; p.bn3b = bn3_b;
    p.stats = stats; p.bar = bar; p.out = (float*)d_out;
    void* args[] = {&p};
    hipError_t e = hipLaunchCooperativeKernel(
        reinterpret_cast<void*>(k_fused), dim3(NBLK), dim3(256), args, 0,
        stream);
    launched = (e == hipSuccess);
  }

  if (!launched) {  // fallback: round-2 multi-kernel path
    k_cheb1<<<NG, 256, 0, stream>>>(feat, src, W1h, W1l, cheb1_b, bufA,
                                    stats + 0 * NREP * 128);
    k_econv<<<NG, 256, 0, stream>>>(bufA, stats + 0 * NREP * 128, bn1_g, bn1_b,
                                    src, T1h, T1l, P1h, P1l, e1_tb, e1_pb,
                                    bufB, stats + 1 * NREP * 128);
    k_cheb64<<<NG, 256, 0, stream>>>(bufB, stats + 1 * NREP * 128, bne1_g,
                                     bne1_b, src, W2h, W2l, cheb2_b, bufA,
                                     stats + 2 * NREP * 128);
    k_econv<<<NG, 256, 0, stream>>>(bufA, stats + 2 * NREP * 128, bn2_g, bn2_b,
                                    src, T2h, T2l, P2h, P2l, e2_tb, e2_pb,
                                    bufB, stats + 3 * NREP * 128);
    k_cheb64<<<NG, 256, 0, stream>>>(bufB, stats + 3 * NREP * 128, bne2_g,
                                     bne2_b, src, W3h, W3l, cheb3_b, bufA,
                                     stats + 4 * NREP * 128);
    k_pool<<<NG, 256, 0, stream>>>(bufA, stats + 4 * NREP * 128, bn3_g, bn3_b,
                                   (float*)d_out);
  }
}

// Round 5
// 277.203 us; speedup vs baseline: 2.4443x; 1.5619x over previous
//
#include <hip/hip_runtime.h>

#define NN 65536
#define PP 64
#define HH 64
#define FINN 16
#define NBLK 512  // 2 blocks/CU x 256 CUs: co-resident by capacity
#define EPSF 1e-5f
#define C1 0.0625f
#define NREP 32  // stats accumulator replicas (contention spread)

typedef short bf16x8 __attribute__((ext_vector_type(8)));
typedef short s16x4 __attribute__((ext_vector_type(4)));
typedef float f32x4 __attribute__((ext_vector_type(4)));
typedef unsigned short u16;

#define MFMA(a, b, c) __builtin_amdgcn_mfma_f32_16x16x32_bf16(a, b, c, 0, 0, 0)

__device__ __forceinline__ u16 f2bf(float x) {
  union { float f; unsigned u; } v; v.f = x; return (u16)(v.u >> 16);
}
__device__ __forceinline__ float bf2f(u16 h) {
  union { float f; unsigned u; } v; v.u = ((unsigned)h) << 16; return v.f;
}
__device__ __forceinline__ void split2(float x, u16& h, u16& l) {
  h = f2bf(x); l = f2bf(x - bf2f(h));
}
// swizzled index into a 64x64 u16 LDS tile: 16B granules XOR'd by row&7
__device__ __forceinline__ int XIDX(int r, int c) {
  return r * 64 + ((((c >> 3) ^ (r & 7)) << 3) | (c & 7));
}

// Build local adjacency (multiplicity) for this graph into Adj (bf16, swizzled).
__device__ __forceinline__ void build_adj(const int* __restrict__ src, int g,
                                          int r, u16* Adj) {
  bf16x8 z = {0, 0, 0, 0, 0, 0, 0, 0};
#pragma unroll
  for (int q = 0; q < 8; q++) *(bf16x8*)&Adj[r * 64 + q * 8] = z;
  const int4* s4 = (const int4*)(src + (size_t)g * 1024 + (size_t)r * 16);
  int4 a0 = s4[0], a1 = s4[1], a2 = s4[2], a3 = s4[3];
  int b0 = g * 64;
  int ss[16] = {a0.x - b0, a0.y - b0, a0.z - b0, a0.w - b0,
                a1.x - b0, a1.y - b0, a1.z - b0, a1.w - b0,
                a2.x - b0, a2.y - b0, a2.z - b0, a2.w - b0,
                a3.x - b0, a3.y - b0, a3.z - b0, a3.w - b0};
#pragma unroll
  for (int e = 0; e < 16; e++) {
    int idx = XIDX(r, ss[e]);
    Adj[idx] = f2bf(bf2f(Adj[idx]) + 1.0f);
  }
}

// ===========================================================================
// FUSED KERNEL, plain (non-cooperative) launch: 512 blocks x 256 threads with
// __launch_bounds__(256,2) on 256 CUs -> all blocks resident by capacity.
// Block b owns graphs 2b, 2b+1. Pre-BN activations live in registers.
// Cross-block communication is EXCLUSIVELY via L3-point atomics:
//   - stats writes: device-scope atomicAdd (32 replicas, contention-spread)
//   - stats reads: agent-scope RELAXED atomic loads (bypass non-coherent L2)
//   - barrier: RELAXED fetch_add + RELAXED spin. NO acquire/release cache
//     maintenance anywhere (round-4 lesson: agent-ACQUIRE spin loads emit
//     per-poll L2 invalidates -> ~27us/barrier of L2-invalidate storms).
// __syncthreads before arrival drains vmcnt -> stats atomics are at L3.
// Spin has an s_memrealtime timeout escape so a residency failure fails
// visibly rather than hanging the harness.
// ===========================================================================
struct KP {
  const float* feat; const int* src;
  const u16 *W1h, *W1l, *W2h, *W2l, *W3h, *W3l;
  const u16 *T1h, *T1l, *P1h, *P1l, *T2h, *T2l, *P2h, *P2l;
  const float *c1b, *bn1g, *bn1b;
  const float *e1tb, *e1pb, *bne1g, *bne1b;
  const float *c2b, *bn2g, *bn2b;
  const float *e2tb, *e2pb, *bne2g, *bne2b;
  const float *c3b, *bn3g, *bn3b;
  float* stats;   // 5 x NREP x 128
  unsigned* bar;  // 8 barrier counters (zeroed by k_prep each iteration)
  float* out;
};

__global__ __launch_bounds__(256, 2) void k_fused(KP p) {
  // 56 KB LDS pool, manually laid out (aliased between cheb and econv):
  //  [0..4095]=NMh [4096..8191]=NMl [8192..12287]=X0h [12288..16383]=X0l
  //  [16384..20479]=X1h [20480..24575]=X1l [24576..28671]=Adj
  //  econv aliases: Tf(float[64*68]) over X0h..X1h, sW(u32[256]) over X1l
  __shared__ __align__(16) u16 SH[28672];
  __shared__ float sstats[128];
  u16* NMh = SH;
  u16* NMl = SH + 4096;
  u16* X0h = SH + 8192;
  u16* X0l = SH + 12288;
  u16* X1h = SH + 16384;
  u16* X1l = SH + 20480;
  u16* Adj = SH + 24576;
  float* Tf = (float*)(SH + 8192);
  unsigned* sW = (unsigned*)(SH + 20480);

  const int t = threadIdx.x;
  const int L = t & 63;
  const int w = __builtin_amdgcn_readfirstlane(t >> 6);
  const int ml = L & 15, kq = L >> 4;
  const int c0 = w * 16 + kq * 4;  // this thread's 4 output channels

  f32x4 ya[4], yb[4];  // pre-BN y frags: [nt] -> node nt*16+ml, chans c0..c0+3
  const int ga = blockIdx.x * 2, gb = ga + 1;

  // RELAXED grid barrier on counter i (all cross-block data is L3 atomics, so
  // no cache maintenance needed). s_sleep(8) ~0.2us poll granularity keeps the
  // 512-spinner L3 poll traffic low. Timeout escape ~40ms (realtime ~100MHz).
  auto gbar = [&](int i) {
    __syncthreads();
    if (t == 0) {
      unsigned* c = p.bar + i;
      __hip_atomic_fetch_add(c, 1u, __ATOMIC_RELAXED,
                             __HIP_MEMORY_SCOPE_AGENT);
      unsigned long long tstart = __builtin_amdgcn_s_memrealtime();
      while (__hip_atomic_load(c, __ATOMIC_RELAXED,
                               __HIP_MEMORY_SCOPE_AGENT) < (unsigned)NBLK) {
        __builtin_amdgcn_s_sleep(8);
        if (__builtin_amdgcn_s_memrealtime() - tstart > 4000000ull) break;
      }
    }
    __syncthreads();
  };

  // Replica-sum this boundary's stats into LDS. Agent-scope atomic loads
  // bypass the (non-coherent) local L2 so post-barrier values are seen.
  auto rep_red = [&](const float* sb) {
    if (t < 128) {
      float s = 0.f;
#pragma unroll
      for (int r = 0; r < NREP; r++)
        s += __hip_atomic_load(sb + (size_t)r * 128 + t, __ATOMIC_RELAXED,
                               __HIP_MEMORY_SCOPE_AGENT);
      sstats[t] = s;
    }
  };

  auto stats_acc = [&](f32x4 (&y)[4], int g, float* so) {
    float s1[4] = {0, 0, 0, 0}, s2[4] = {0, 0, 0, 0};
#pragma unroll
    for (int nt = 0; nt < 4; nt++)
#pragma unroll
      for (int i = 0; i < 4; i++) {
        s1[i] += y[nt][i];
        s2[i] += y[nt][i] * y[nt][i];
      }
#pragma unroll
    for (int i = 0; i < 4; i++)
#pragma unroll
      for (int off = 1; off < 16; off <<= 1) {
        s1[i] += __shfl_xor(s1[i], off, 64);
        s2[i] += __shfl_xor(s2[i], off, 64);
      }
    if (ml == 0) {
      float* pr = so + (size_t)(g & (NREP - 1)) * 128 + c0;
#pragma unroll
      for (int i = 0; i < 4; i++) {
        atomicAdd(pr + i, s1[i]);
        atomicAdd(pr + 64 + i, s2[i]);
      }
    }
  };

  // BN+ReLU directly from accumulator frags -> split-bf16 LDS tiles.
  auto bn_frag = [&](f32x4 (&y)[4], const float* gam, const float* bet,
                     u16* CMh, u16* CMl) {
    const float inv = 1.0f / (float)NN;
    float sc[4], sh[4];
#pragma unroll
    for (int i = 0; i < 4; i++) {
      int c = c0 + i;
      float s1 = sstats[c], s2 = sstats[64 + c];
      float mu = s1 * inv;
      float var = fmaf(s2, inv, -mu * mu);
      sc[i] = gam[c] * rsqrtf(var + EPSF);
      sh[i] = fmaf(-mu, sc[i], bet[c]);
    }
#pragma unroll
    for (int nt = 0; nt < 4; nt++) {
      int node = nt * 16 + ml;
      u16 hh[4], ll[4];
      s16x4 vh, vl;
#pragma unroll
      for (int i = 0; i < 4; i++) {
        float h = fmaxf(fmaf(sc[i], y[nt][i], sh[i]), 0.f);
        split2(h, hh[i], ll[i]);
        vh[i] = (short)hh[i]; vl[i] = (short)ll[i];
      }
      *(s16x4*)&NMh[XIDX(node, c0)] = vh;
      *(s16x4*)&NMl[XIDX(node, c0)] = vl;
      if (CMh) {
#pragma unroll
        for (int i = 0; i < 4; i++) {
          CMh[XIDX(c0 + i, node)] = hh[i];
          CMl[XIDX(c0 + i, node)] = ll[i];
        }
      }
    }
  };

  // ---- cheb layer CI=64 (W folded [W0-W2|W1|W2], K=192) ----
  auto cheb64_graph = [&](int g, f32x4 (&y)[4], const u16* wh, const u16* wl,
                          const float* bias, const float* gam,
                          const float* bet, float* so) {
    bn_frag(y, gam, bet, X0h, X0l);
    if (w == 3) build_adj(p.src, g, L, Adj);
    __syncthreads();

    f32x4 acc[4] = {};
    auto yacc = [&](int kbase) {
      const u16* whp = wh + (size_t)(w * 16 + ml) * 192 + kq * 8 + kbase;
      const u16* wlp = wl + (size_t)(w * 16 + ml) * 192 + kq * 8 + kbase;
#pragma unroll
      for (int kt = 0; kt < 2; kt++) {
        bf16x8 ah = *(const bf16x8*)(whp + kt * 32);
        bf16x8 al = *(const bf16x8*)(wlp + kt * 32);
        int kk = kt * 32 + kq * 8;
#pragma unroll
        for (int nt = 0; nt < 4; nt++) {
          bf16x8 bh = *(const bf16x8*)&NMh[XIDX(nt * 16 + ml, kk)];
          bf16x8 bl = *(const bf16x8*)&NMl[XIDX(nt * 16 + ml, kk)];
          acc[nt] = MFMA(ah, bh, acc[nt]);
          acc[nt] = MFMA(al, bh, acc[nt]);
          acc[nt] = MFMA(ah, bl, acc[nt]);
        }
      }
    };
    auto lap = [&](const u16* Bh, const u16* Bl, float scale, u16* oCh,
                   u16* oCl) {
      f32x4 l[4] = {};
#pragma unroll
      for (int kt = 0; kt < 2; kt++) {
        int kk = kt * 32 + kq * 8;
        bf16x8 aa = *(const bf16x8*)&Adj[XIDX(w * 16 + ml, kk)];
#pragma unroll
        for (int nt = 0; nt < 4; nt++) {
          bf16x8 bh = *(const bf16x8*)&Bh[XIDX(nt * 16 + ml, kk)];
          bf16x8 bl = *(const bf16x8*)&Bl[XIDX(nt * 16 + ml, kk)];
          l[nt] = MFMA(aa, bh, l[nt]);
          l[nt] = MFMA(aa, bl, l[nt]);
        }
      }
      int r0 = w * 16 + kq * 4;
#pragma unroll
      for (int nt = 0; nt < 4; nt++) {
        int c = nt * 16 + ml;
        u16 hh[4], ll[4];
#pragma unroll
        for (int i = 0; i < 4; i++) {
          split2(l[nt][i] * scale, hh[i], ll[i]);
          NMh[XIDX(r0 + i, c)] = hh[i];
          NMl[XIDX(r0 + i, c)] = ll[i];
        }
        if (oCh) {
          s16x4 vh, vl;
#pragma unroll
          for (int i = 0; i < 4; i++) {
            vh[i] = (short)hh[i]; vl[i] = (short)ll[i];
          }
          *(s16x4*)&oCh[XIDX(c, r0)] = vh;
          *(s16x4*)&oCl[XIDX(c, r0)] = vl;
        }
      }
    };

    yacc(0);                       // X0 vs W0' = W0 - W2
    __syncthreads();
    lap(X0h, X0l, -C1, X1h, X1l);  // X1 = -C1*Adj*X0
    __syncthreads();
    yacc(64);                      // X1 vs W1
    __syncthreads();
    lap(X1h, X1l, -2.0f * C1, nullptr, nullptr);  // Z2 = -2C1*Adj*X1
    __syncthreads();
    yacc(128);                     // Z2 vs W2
    float4 bb = *(const float4*)(bias + c0);
#pragma unroll
    for (int nt = 0; nt < 4; nt++) {
      y[nt][0] = acc[nt][0] + bb.x;
      y[nt][1] = acc[nt][1] + bb.y;
      y[nt][2] = acc[nt][2] + bb.z;
      y[nt][3] = acc[nt][3] + bb.w;
    }
    stats_acc(y, g, so);
  };

  // ---- econv layer ----
  auto econv_graph = [&](int g, f32x4 (&y)[4], const u16* twh, const u16* twl,
                         const u16* pwh, const u16* pwl, const float* tb,
                         const float* pb, const float* gam, const float* bet,
                         float* so) {
    bn_frag(y, gam, bet, nullptr, nullptr);
    {
      int4 v = ((const int4*)(p.src + (size_t)g * 1024))[t];
      int b0 = g * 64;
      sW[t] = (unsigned)(v.x - b0) | ((unsigned)(v.y - b0) << 8) |
              ((unsigned)(v.z - b0) << 16) | ((unsigned)(v.w - b0) << 24);
    }
    __syncthreads();

    f32x4 tA[4] = {}, pA[4] = {};
    const size_t wrow = (size_t)(w * 16 + ml) * 64 + kq * 8;
#pragma unroll
    for (int kt = 0; kt < 2; kt++) {
      bf16x8 ath = *(const bf16x8*)(twh + wrow + kt * 32);
      bf16x8 atl = *(const bf16x8*)(twl + wrow + kt * 32);
      bf16x8 aph = *(const bf16x8*)(pwh + wrow + kt * 32);
      bf16x8 apl = *(const bf16x8*)(pwl + wrow + kt * 32);
      int kk = kt * 32 + kq * 8;
#pragma unroll
      for (int nt = 0; nt < 4; nt++) {
        bf16x8 bh = *(const bf16x8*)&NMh[XIDX(nt * 16 + ml, kk)];
        bf16x8 bl = *(const bf16x8*)&NMl[XIDX(nt * 16 + ml, kk)];
        tA[nt] = MFMA(ath, bh, tA[nt]);
        tA[nt] = MFMA(atl, bh, tA[nt]);
        tA[nt] = MFMA(ath, bl, tA[nt]);
        pA[nt] = MFMA(aph, bh, pA[nt]);
        pA[nt] = MFMA(apl, bh, pA[nt]);
        pA[nt] = MFMA(aph, bl, pA[nt]);
      }
    }
    // T -> LDS [node][ch] stride 68 (own-wave cols; wave-order write->read ok)
#pragma unroll
    for (int nt = 0; nt < 4; nt++) {
      int n = nt * 16 + ml;
      float4 v;
      v.x = tA[nt][0]; v.y = tA[nt][1]; v.z = tA[nt][2]; v.w = tA[nt][3];
      *(float4*)&Tf[n * 68 + c0] = v;
    }
    float4 tbv = *(const float4*)(tb + c0);
    float4 pbv = *(const float4*)(pb + c0);
#pragma unroll
    for (int nt = 0; nt < 4; nt++) {
      int n = nt * 16 + ml;
      unsigned w0 = sW[n * 4], w1 = sW[n * 4 + 1], w2 = sW[n * 4 + 2],
               w3 = sW[n * 4 + 3];
      float4 mn = {3.4e38f, 3.4e38f, 3.4e38f, 3.4e38f};
#pragma unroll
      for (int e = 0; e < 16; e++) {
        unsigned wd = (e < 4) ? w0 : (e < 8) ? w1 : (e < 12) ? w2 : w3;
        int s = (wd >> ((e & 3) * 8)) & 255;
        float4 tv = *(const float4*)&Tf[s * 68 + c0];
        mn.x = fminf(mn.x, tv.x); mn.y = fminf(mn.y, tv.y);
        mn.z = fminf(mn.z, tv.z); mn.w = fminf(mn.w, tv.w);
      }
      y[nt][0] = tA[nt][0] + pA[nt][0] + tbv.x + pbv.x - mn.x;
      y[nt][1] = tA[nt][1] + pA[nt][1] + tbv.y + pbv.y - mn.y;
      y[nt][2] = tA[nt][2] + pA[nt][2] + tbv.z + pbv.z - mn.z;
      y[nt][3] = tA[nt][3] + pA[nt][3] + tbv.w + pbv.w - mn.w;
    }
    stats_acc(y, g, so);
  };

  // ---- cheb layer 1 (feat input, FIN=16, K padded to 64) ----
  auto cheb1_graph = [&](int g, f32x4 (&y)[4]) {
    {
      int n = t >> 2, cc = (t & 3) * 4;
      float4 v = *(const float4*)(p.feat + (size_t)(g * 64 + n) * 16 + cc);
      u16 hh[4], ll[4];
      split2(v.x, hh[0], ll[0]); split2(v.y, hh[1], ll[1]);
      split2(v.z, hh[2], ll[2]); split2(v.w, hh[3], ll[3]);
      s16x4 vh, vl;
#pragma unroll
      for (int i = 0; i < 4; i++) { vh[i] = (short)hh[i]; vl[i] = (short)ll[i]; }
      *(s16x4*)&NMh[XIDX(n, cc)] = vh;
      *(s16x4*)&NMl[XIDX(n, cc)] = vl;
#pragma unroll
      for (int i = 0; i < 4; i++) {
        X0h[XIDX(cc + i, n)] = hh[i];
        X0l[XIDX(cc + i, n)] = ll[i];
      }
    }
    if (w == 0) {
      bf16x8 z = {0, 0, 0, 0, 0, 0, 0, 0};
      *(bf16x8*)&NMh[XIDX(L, 48)] = z;
      *(bf16x8*)&NMh[XIDX(L, 56)] = z;
    } else if (w == 1) {
      bf16x8 z = {0, 0, 0, 0, 0, 0, 0, 0};
      *(bf16x8*)&NMl[XIDX(L, 48)] = z;
      *(bf16x8*)&NMl[XIDX(L, 56)] = z;
    } else if (w == 3) {
      build_adj(p.src, g, L, Adj);
    }
    __syncthreads();
    {  // lap1: X1 = -C1*Adj*X0 -> NM cols 16..31, CM rows 16..31
      f32x4 l0 = {};
#pragma unroll
      for (int kt = 0; kt < 2; kt++) {
        int kk = kt * 32 + kq * 8;
        bf16x8 aa = *(const bf16x8*)&Adj[XIDX(w * 16 + ml, kk)];
        bf16x8 bh = *(const bf16x8*)&X0h[XIDX(ml, kk)];
        bf16x8 bl = *(const bf16x8*)&X0l[XIDX(ml, kk)];
        l0 = MFMA(aa, bh, l0);
        l0 = MFMA(aa, bl, l0);
      }
      int r0 = w * 16 + kq * 4;
      u16 hh[4], ll[4];
#pragma unroll
      for (int i = 0; i < 4; i++) {
        split2(l0[i] * (-C1), hh[i], ll[i]);
        NMh[XIDX(r0 + i, 16 + ml)] = hh[i];
        NMl[XIDX(r0 + i, 16 + ml)] = ll[i];
      }
      s16x4 vh, vl;
#pragma unroll
      for (int i = 0; i < 4; i++) { vh[i] = (short)hh[i]; vl[i] = (short)ll[i]; }
      *(s16x4*)&X0h[XIDX(16 + ml, r0)] = vh;
      *(s16x4*)&X0l[XIDX(16 + ml, r0)] = vl;
    }
    __syncthreads();
    {  // lap2: Z2 = -2C1*Adj*X1 -> NM cols 32..47
      f32x4 l0 = {};
#pragma unroll
      for (int kt = 0; kt < 2; kt++) {
        int kk = kt * 32 + kq * 8;
        bf16x8 aa = *(const bf16x8*)&Adj[XIDX(w * 16 + ml, kk)];
        bf16x8 bh = *(const bf16x8*)&X0h[XIDX(16 + ml, kk)];
        bf16x8 bl = *(const bf16x8*)&X0l[XIDX(16 + ml, kk)];
        l0 = MFMA(aa, bh, l0);
        l0 = MFMA(aa, bl, l0);
      }
      int r0 = w * 16 + kq * 4;
      u16 hh[4], ll[4];
#pragma unroll
      for (int i = 0; i < 4; i++) {
        split2(l0[i] * (-2.0f * C1), hh[i], ll[i]);
        NMh[XIDX(r0 + i, 32 + ml)] = hh[i];
        NMl[XIDX(r0 + i, 32 + ml)] = ll[i];
      }
    }
    __syncthreads();
    f32x4 acc[4] = {};
    const u16* whp = p.W1h + (size_t)(w * 16 + ml) * 64 + kq * 8;
    const u16* wlp = p.W1l + (size_t)(w * 16 + ml) * 64 + kq * 8;
#pragma unroll
    for (int kt = 0; kt < 2; kt++) {
      bf16x8 ah = *(const bf16x8*)(whp + kt * 32);
      bf16x8 al = *(const bf16x8*)(wlp + kt * 32);
      int kk = kt * 32 + kq * 8;
#pragma unroll
      for (int nt = 0; nt < 4; nt++) {
        bf16x8 bh = *(const bf16x8*)&NMh[XIDX(nt * 16 + ml, kk)];
        bf16x8 bl = *(const bf16x8*)&NMl[XIDX(nt * 16 + ml, kk)];
        acc[nt] = MFMA(ah, bh, acc[nt]);
        acc[nt] = MFMA(al, bh, acc[nt]);
        acc[nt] = MFMA(ah, bl, acc[nt]);
      }
    }
    float4 bb = *(const float4*)(p.c1b + c0);
#pragma unroll
    for (int nt = 0; nt < 4; nt++) {
      y[nt][0] = acc[nt][0] + bb.x;
      y[nt][1] = acc[nt][1] + bb.y;
      y[nt][2] = acc[nt][2] + bb.z;
      y[nt][3] = acc[nt][3] + bb.w;
    }
    stats_acc(y, g, p.stats);
  };

  // ---- final BN+ReLU + mean pool from frags ----
  auto pool_graph = [&](int g, f32x4 (&y)[4], const float* gam,
                        const float* bet) {
    const float inv = 1.0f / (float)NN;
    float sc[4], sh[4];
#pragma unroll
    for (int i = 0; i < 4; i++) {
      int c = c0 + i;
      float s1 = sstats[c], s2 = sstats[64 + c];
      float mu = s1 * inv;
      float var = fmaf(s2, inv, -mu * mu);
      sc[i] = gam[c] * rsqrtf(var + EPSF);
      sh[i] = fmaf(-mu, sc[i], bet[c]);
    }
    float s[4] = {0, 0, 0, 0};
#pragma unroll
    for (int nt = 0; nt < 4; nt++)
#pragma unroll
      for (int i = 0; i < 4; i++)
        s[i] += fmaxf(fmaf(sc[i], y[nt][i], sh[i]), 0.f);
#pragma unroll
    for (int i = 0; i < 4; i++)
#pragma unroll
      for (int off = 1; off < 16; off <<= 1) s[i] += __shfl_xor(s[i], off, 64);
    if (ml == 0) {
      float4 o = make_float4(s[0] * (1.f / 64.f), s[1] * (1.f / 64.f),
                             s[2] * (1.f / 64.f), s[3] * (1.f / 64.f));
      *(float4*)(p.out + (size_t)g * 64 + c0) = o;
    }
  };

  // ======================= network =======================
  // L1: cheb1 (stats boundary 0)
  cheb1_graph(ga, ya);
  __syncthreads();
  cheb1_graph(gb, yb);
  gbar(0);
  // L2: econv1 (bn1; stats boundary 1)
  rep_red(p.stats + 0);
  __syncthreads();
  econv_graph(ga, ya, p.T1h, p.T1l, p.P1h, p.P1l, p.e1tb, p.e1pb, p.bn1g,
              p.bn1b, p.stats + (size_t)1 * NREP * 128);
  __syncthreads();
  econv_graph(gb, yb, p.T1h, p.T1l, p.P1h, p.P1l, p.e1tb, p.e1pb, p.bn1g,
              p.bn1b, p.stats + (size_t)1 * NREP * 128);
  gbar(1);
  // L3: cheb2 (bne1; stats boundary 2)
  rep_red(p.stats + (size_t)1 * NREP * 128);
  __syncthreads();
  cheb64_graph(ga, ya, p.W2h, p.W2l, p.c2b, p.bne1g, p.bne1b,
               p.stats + (size_t)2 * NREP * 128);
  __syncthreads();
  cheb64_graph(gb, yb, p.W2h, p.W2l, p.c2b, p.bne1g, p.bne1b,
               p.stats + (size_t)2 * NREP * 128);
  gbar(2);
  // L4: econv2 (bn2; stats boundary 3)
  rep_red(p.stats + (size_t)2 * NREP * 128);
  __syncthreads();
  econv_graph(ga, ya, p.T2h, p.T2l, p.P2h, p.P2l, p.e2tb, p.e2pb, p.bn2g,
              p.bn2b, p.stats + (size_t)3 * NREP * 128);
  __syncthreads();
  econv_graph(gb, yb, p.T2h, p.T2l, p.P2h, p.P2l, p.e2tb, p.e2pb, p.bn2g,
              p.bn2b, p.stats + (size_t)3 * NREP * 128);
  gbar(3);
  // L5: cheb3 (bne2; stats boundary 4)
  rep_red(p.stats + (size_t)3 * NREP * 128);
  __syncthreads();
  cheb64_graph(ga, ya, p.W3h, p.W3l, p.c3b, p.bne2g, p.bne2b,
               p.stats + (size_t)4 * NREP * 128);
  __syncthreads();
  cheb64_graph(gb, yb, p.W3h, p.W3l, p.c3b, p.bne2g, p.bne2b,
               p.stats + (size_t)4 * NREP * 128);
  gbar(4);
  // pool (bn3)
  rep_red(p.stats + (size_t)4 * NREP * 128);
  __syncthreads();
  pool_graph(ga, ya, p.bn3g, p.bn3b);
  pool_graph(gb, yb, p.bn3g, p.bn3b);
}

// ---------------------------------------------------------------------------
// Weight prep: fold recurrence, pad, split to bf16 hi/lo; zero replica stats
// and the 8 grid-barrier counters. Runs as its OWN dispatch so the
// kernel-boundary flush publishes everything coherently before k_fused.
// ---------------------------------------------------------------------------
__global__ void k_prep(const float* __restrict__ c1w, const float* __restrict__ c2w,
                       const float* __restrict__ c3w, const float* __restrict__ e1t,
                       const float* __restrict__ e1p, const float* __restrict__ e2t,
                       const float* __restrict__ e2p, u16* __restrict__ W1h,
                       u16* __restrict__ W1l, u16* __restrict__ W2h,
                       u16* __restrict__ W2l, u16* __restrict__ W3h,
                       u16* __restrict__ W3l, u16* __restrict__ T1h,
                       u16* __restrict__ T1l, u16* __restrict__ P1h,
                       u16* __restrict__ P1l, u16* __restrict__ T2h,
                       u16* __restrict__ T2l, u16* __restrict__ P2h,
                       u16* __restrict__ P2l, float* __restrict__ stats,
                       unsigned* __restrict__ bar) {
  int t0 = blockIdx.x * 256 + threadIdx.x;
  int stride = gridDim.x * 256;
  for (int i = t0; i < 5 * NREP * 128; i += stride) stats[i] = 0.f;
  if (t0 < 8) bar[t0] = 0u;
  for (int i = t0; i < 4096; i += stride) {
    int r = i >> 6, c = i & 63;
    float v = 0.f;
    if (c < 16) v = c1w[r * 48 + c] - c1w[r * 48 + 32 + c];
    else if (c < 48) v = c1w[r * 48 + c];
    u16 h, l; split2(v, h, l); W1h[i] = h; W1l[i] = l;
  }
  for (int i = t0; i < 12288; i += stride) {
    int r = i / 192, c = i - r * 192;
    float v = (c < 64) ? c2w[r * 192 + c] - c2w[r * 192 + 128 + c]
                       : c2w[r * 192 + c];
    u16 h, l; split2(v, h, l); W2h[i] = h; W2l[i] = l;
  }
  for (int i = t0; i < 12288; i += stride) {
    int r = i / 192, c = i - r * 192;
    float v = (c < 64) ? c3w[r * 192 + c] - c3w[r * 192 + 128 + c]
                       : c3w[r * 192 + c];
    u16 h, l; split2(v, h, l); W3h[i] = h; W3l[i] = l;
  }
  for (int i = t0; i < 4096; i += stride) {
    u16 h, l;
    split2(e1t[i], h, l); T1h[i] = h; T1l[i] = l;
    split2(e1p[i], h, l); P1h[i] = h; P1l[i] = l;
    split2(e2t[i], h, l); T2h[i] = h; T2l[i] = l;
    split2(e2p[i], h, l); P2h[i] = h; P2l[i] = l;
  }
}

// ---------------------------------------------------------------------------
extern "C" void kernel_launch(void* const* d_in, const int* in_sizes, int n_in,
                              void* d_out, int out_size, void* d_ws,
                              size_t ws_size, hipStream_t stream) {
  const float* feat = (const float*)d_in[0];
  const int* src = (const int*)d_in[1];
  const float* cheb1_w = (const float*)d_in[4];
  const float* cheb1_b = (const float*)d_in[5];
  const float* bn1_g = (const float*)d_in[6];
  const float* bn1_b = (const float*)d_in[7];
  const float* e1_tw = (const float*)d_in[8];
  const float* e1_tb = (const float*)d_in[9];
  const float* e1_pw = (const float*)d_in[10];
  const float* e1_pb = (const float*)d_in[11];
  const float* bne1_g = (const float*)d_in[12];
  const float* bne1_b = (const float*)d_in[13];
  const float* cheb2_w = (const float*)d_in[14];
  const float* cheb2_b = (const float*)d_in[15];
  const float* bn2_g = (const float*)d_in[16];
  const float* bn2_b = (const float*)d_in[17];
  const float* e2_tw = (const float*)d_in[18];
  const float* e2_tb = (const float*)d_in[19];
  const float* e2_pw = (const float*)d_in[20];
  const float* e2_pb = (const float*)d_in[21];
  const float* bne2_g = (const float*)d_in[22];
  const float* bne2_b = (const float*)d_in[23];
  const float* cheb3_w = (const float*)d_in[24];
  const float* cheb3_b = (const float*)d_in[25];
  const float* bn3_g = (const float*)d_in[26];
  const float* bn3_b = (const float*)d_in[27];

  float* stats = (float*)d_ws;  // 5 x NREP x 128 replica stats
  unsigned* bar = (unsigned*)(stats + 5 * NREP * 128);  // 8 barrier counters
  u16* wq = (u16*)(bar + 8);
  u16* W1h = wq;           u16* W1l = W1h + 4096;
  u16* W2h = W1l + 4096;   u16* W2l = W2h + 12288;
  u16* W3h = W2l + 12288;  u16* W3l = W3h + 12288;
  u16* T1h = W3l + 12288;  u16* T1l = T1h + 4096;
  u16* P1h = T1l + 4096;   u16* P1l = P1h + 4096;
  u16* T2h = P1l + 4096;   u16* T2l = T2h + 4096;
  u16* P2h = T2l + 4096;   u16* P2l = P2h + 4096;

  k_prep<<<16, 256, 0, stream>>>(cheb1_w, cheb2_w, cheb3_w, e1_tw, e1_pw,
                                 e2_tw, e2_pw, W1h, W1l, W2h, W2l, W3h, W3l,
                                 T1h, T1l, P1h, P1l, T2h, T2l, P2h, P2l,
                                 stats, bar);

  KP p;
  p.feat = feat; p.src = src;
  p.W1h = W1h; p.W1l = W1l; p.W2h = W2h; p.W2l = W2l; p.W3h = W3h; p.W3l = W3l;
  p.T1h = T1h; p.T1l = T1l; p.P1h = P1h; p.P1l = P1l;
  p.T2h = T2h; p.T2l = T2l; p.P2h = P2h; p.P2l = P2l;
  p.c1b = cheb1_b; p.bn1g = bn1_g; p.bn1b = bn1_b;
  p.e1tb = e1_tb; p.e1pb = e1_pb; p.bne1g = bne1_g; p.bne1b = bne1_b;
  p.c2b = cheb2_b; p.bn2g = bn2_g; p.bn2b = bn2_b;
  p.e2tb = e2_tb; p.e2pb = e2_pb; p.bne2g = bne2_g; p.bne2b = bne2_b;
  p.c3b = cheb3_b; p.bn3g = bn3_g; p.bn3b = bn3_b;
  p.stats = stats; p.bar = bar; p.out = (float*)d_out;

  // Plain launch: 512 blocks @ __launch_bounds__(256,2) on 256 CUs -> all
  // resident by capacity (exclusive GPU); custom relaxed barrier inside.
  k_fused<<<NBLK, 256, 0, stream>>>(p);
}